// Round 10
// baseline (391.137 us; speedup 1.0000x reference)
//
#include <hip/hip_runtime.h>
#include <math.h>

// Problem constants
#define BB 8
#define LL 512
#define UU 24
#define DD 1024
#define HH 16
#define DH 64
#define TT 72
#define CSKN 1024
#define NVOCAB 54945

typedef __attribute__((ext_vector_type(8))) short bf16x8;
typedef __attribute__((ext_vector_type(4))) float f32x4;

__device__ inline unsigned short f2b(float x) {
    unsigned u = __float_as_uint(x);
    unsigned r = u + 0x7FFFu + ((u >> 16) & 1u);
    return (unsigned short)(r >> 16);
}
__device__ inline unsigned pack2(float lo, float hi) {
    return (unsigned)f2b(lo) | ((unsigned)f2b(hi) << 16);
}
__device__ inline void dec8(uint2 c, float* cr) {
    cr[0] = (float)( c.x        & 0xff); cr[1] = (float)((c.x >>  8) & 0xff);
    cr[2] = (float)((c.x >> 16) & 0xff); cr[3] = (float)((c.x >> 24) & 0xff);
    cr[4] = (float)( c.y        & 0xff); cr[5] = (float)((c.y >>  8) & 0xff);
    cr[6] = (float)((c.y >> 16) & 0xff); cr[7] = (float)((c.y >> 24) & 0xff);
}

// ---------------------------------------------------------------------------
__global__ __launch_bounds__(256) void k_gather_cls(const float* __restrict__ hidden,
        const int* __restrict__ idx, float* __restrict__ sem_cls, float* __restrict__ trans_in)
{
    int bid = blockIdx.x; int b = bid / UU, u = bid % UU;
    int row = idx[b*UU + u];
    const float* src = hidden + ((size_t)(b*LL + row))*DD;
    float* d0 = trans_in + ((size_t)(b*TT + 3*u))*DD;
    float* sc = sem_cls + ((size_t)(b*UU + u))*DD;
    for (int d = threadIdx.x; d < DD; d += 256) {
        float v = src[d];
        sc[d] = v;
        d0[d] = v; d0[DD + d] = v; d0[2*DD + d] = v;
    }
}

__global__ void k_bn(const float* __restrict__ x, const float* __restrict__ g,
                     const float* __restrict__ be, const float* __restrict__ mu,
                     const float* __restrict__ var, float* __restrict__ y, int n)
{
    int i = blockIdx.x*256 + threadIdx.x;
    if (i >= n) return;
    int c = i % CSKN;
    y[i] = (x[i] - mu[c]) * (1.0f/sqrtf(var[c] + 1e-5f)) * g[c] + be[c];
}

// ---------------------------------------------------------------------------
// Double-buffered MFMA bf16 GEMM, 64x64 tile, 256 thr, 4 waves (2x2).
// EPI: 3 = gate-blend C=g*ep1+(1-g)*ep2, g=sigmoid(A@B+bias)
//      4 = csk: trans_in[b*72+3u+2][cc] += (A@B+bias), skip u==U-1 (C=trans_in)
template<int EPI>
__global__ __launch_bounds__(256) void mm64(
        const float* __restrict__ A1, const float* __restrict__ A2, int K1,
        const float* __restrict__ Bm, const float* __restrict__ bias,
        const float* __restrict__ ep1, const float* __restrict__ ep2,
        float* __restrict__ C, int N, int K)
{
    __shared__ __align__(16) unsigned short As[2][64][40];
    __shared__ __align__(16) unsigned short Bs[2][64][40];
    int tid = threadIdx.x;
    int wave = tid >> 6, lane = tid & 63;
    int l16 = lane & 15, g = lane >> 4;
    int wm = wave & 1, wn = wave >> 1;
    int row0 = blockIdx.y * 64, col0 = blockIdx.x * 64;

    int ar = tid >> 2, akq = (tid & 3) * 8;
    int bj0 = (tid & 31) * 2, bk0 = (tid >> 5) * 2;
    float4 a0, a1;
    float2 q00, q01, q10, q11;

    auto loadT = [&](int k0) {
        int kk = k0 + akq;
        const float* src = (kk < K1) ? A1 + (size_t)(row0+ar)*K1 + kk
                                     : A2 + (size_t)(row0+ar)*(K-K1) + (kk-K1);
        a0 = *(const float4*)src; a1 = *(const float4*)(src+4);
        const float* bs0 = Bm + (size_t)(k0 + bk0)*N + col0 + bj0;
        q00 = *(const float2*)bs0;       q01 = *(const float2*)(bs0 + N);
        const float* bs1 = bs0 + (size_t)16*N;
        q10 = *(const float2*)bs1;       q11 = *(const float2*)(bs1 + N);
    };
    auto storeT = [&](int buf) {
        unsigned* da = (unsigned*)&As[buf][ar][akq];
        da[0] = pack2(a0.x, a0.y); da[1] = pack2(a0.z, a0.w);
        da[2] = pack2(a1.x, a1.y); da[3] = pack2(a1.z, a1.w);
        *(unsigned*)&Bs[buf][bj0  ][bk0]    = pack2(q00.x, q01.x);
        *(unsigned*)&Bs[buf][bj0+1][bk0]    = pack2(q00.y, q01.y);
        *(unsigned*)&Bs[buf][bj0  ][bk0+16] = pack2(q10.x, q11.x);
        *(unsigned*)&Bs[buf][bj0+1][bk0+16] = pack2(q10.y, q11.y);
    };

    f32x4 acc[2][2] = {};
    loadT(0); storeT(0);
    __syncthreads();
    int nt = K / 32;
    for (int t = 0; t < nt; ++t) {
        int cur = t & 1;
        if (t + 1 < nt) loadT((t+1)*32);
        bf16x8 af[2], bfr[2];
        #pragma unroll
        for (int mf = 0; mf < 2; ++mf) af[mf] = *(const bf16x8*)&As[cur][wm*32 + mf*16 + l16][g*8];
        #pragma unroll
        for (int nf = 0; nf < 2; ++nf) bfr[nf] = *(const bf16x8*)&Bs[cur][wn*32 + nf*16 + l16][g*8];
        #pragma unroll
        for (int mf = 0; mf < 2; ++mf)
            #pragma unroll
            for (int nf = 0; nf < 2; ++nf)
                acc[mf][nf] = __builtin_amdgcn_mfma_f32_16x16x32_bf16(af[mf], bfr[nf], acc[mf][nf], 0, 0, 0);
        if (t + 1 < nt) storeT(cur ^ 1);
        __syncthreads();
    }
    #pragma unroll
    for (int mf = 0; mf < 2; ++mf)
        #pragma unroll
        for (int nf = 0; nf < 2; ++nf) {
            int cc = col0 + wn*32 + nf*16 + l16;
            float bv = bias[cc];
            #pragma unroll
            for (int r = 0; r < 4; ++r) {
                int rr = row0 + wm*32 + mf*16 + g*4 + r;
                float v = acc[mf][nf][r] + bv;
                if (EPI == 3) {
                    float gg = 1.0f/(1.0f + __expf(-v));
                    float tv = ep1[(size_t)rr*N + cc];
                    float iv = ep2[(size_t)rr*N + cc];
                    C[(size_t)rr*N + cc] = gg*tv + (1.0f - gg)*iv;
                } else { // EPI == 4
                    int bq = rr / UU, uq = rr % UU;
                    if (uq < UU-1) {
                        float* dst = &C[((size_t)(bq*TT + 3*uq + 2))*DD + cc];
                        *dst += v;
                    }
                }
            }
        }
}

// ---------------------------------------------------------------------------
// Fused Q/K/V projection, BM=64 BN=128, dbuf. Grid (24, 9); blockIdx.x>>3 selects.
__global__ __launch_bounds__(256) void mm_qkv(
        const float* __restrict__ x,
        const float* __restrict__ W0, const float* __restrict__ W1, const float* __restrict__ W2,
        const float* __restrict__ v0, const float* __restrict__ v1, const float* __restrict__ v2,
        float* __restrict__ C0, float* __restrict__ C1, float* __restrict__ C2)
{
    __shared__ __align__(16) unsigned short As[2][64][40];
    __shared__ __align__(16) unsigned short Bs[2][128][40];
    int which = blockIdx.x >> 3;
    int col0 = (blockIdx.x & 7) * 128;
    int row0 = blockIdx.y * 64;
    const float* W  = (which == 0) ? W0 : (which == 1) ? W1 : W2;
    const float* bb = (which == 0) ? v0 : (which == 1) ? v1 : v2;
    float*       C  = (which == 0) ? C0 : (which == 1) ? C1 : C2;
    int tid = threadIdx.x;
    int wave = tid >> 6, lane = tid & 63;
    int l16 = lane & 15, g = lane >> 4;
    int wm = wave & 1, wn = wave >> 1;

    int ar = tid >> 2, akq = (tid & 3) * 8;
    int bj0 = (tid & 63) * 2, ks = tid >> 6;   // 4 k-pair slots per thread
    float4 a0, a1;
    float2 b0[4], b1[4];

    auto loadT = [&](int k0) {
        const float* src = x + (size_t)(row0+ar)*DD + k0 + akq;
        a0 = *(const float4*)src; a1 = *(const float4*)(src+4);
        #pragma unroll
        for (int s = 0; s < 4; ++s) {
            int kb = (ks + 4*s)*2;
            const float* bp = W + (size_t)(k0 + kb)*DD + col0 + bj0;
            b0[s] = *(const float2*)bp;
            b1[s] = *(const float2*)(bp + DD);
        }
    };
    auto storeT = [&](int buf) {
        unsigned* da = (unsigned*)&As[buf][ar][akq];
        da[0] = pack2(a0.x, a0.y); da[1] = pack2(a0.z, a0.w);
        da[2] = pack2(a1.x, a1.y); da[3] = pack2(a1.z, a1.w);
        #pragma unroll
        for (int s = 0; s < 4; ++s) {
            int kb = (ks + 4*s)*2;
            *(unsigned*)&Bs[buf][bj0  ][kb] = pack2(b0[s].x, b1[s].x);
            *(unsigned*)&Bs[buf][bj0+1][kb] = pack2(b0[s].y, b1[s].y);
        }
    };

    f32x4 acc[2][4] = {};
    loadT(0); storeT(0);
    __syncthreads();
    for (int t = 0; t < 32; ++t) {
        int cur = t & 1;
        if (t < 31) loadT((t+1)*32);
        bf16x8 af[2], bfr[4];
        #pragma unroll
        for (int mf = 0; mf < 2; ++mf) af[mf] = *(const bf16x8*)&As[cur][wm*32 + mf*16 + l16][g*8];
        #pragma unroll
        for (int nf = 0; nf < 4; ++nf) bfr[nf] = *(const bf16x8*)&Bs[cur][wn*64 + nf*16 + l16][g*8];
        #pragma unroll
        for (int mf = 0; mf < 2; ++mf)
            #pragma unroll
            for (int nf = 0; nf < 4; ++nf)
                acc[mf][nf] = __builtin_amdgcn_mfma_f32_16x16x32_bf16(af[mf], bfr[nf], acc[mf][nf], 0, 0, 0);
        if (t < 31) storeT(cur ^ 1);
        __syncthreads();
    }
    #pragma unroll
    for (int mf = 0; mf < 2; ++mf)
        #pragma unroll
        for (int nf = 0; nf < 4; ++nf) {
            int cc = col0 + wn*64 + nf*16 + l16;
            float bv = bb[cc];
            #pragma unroll
            for (int r = 0; r < 4; ++r) {
                int rr = row0 + wm*32 + mf*16 + g*4 + r;
                C[(size_t)rr*DD + cc] = acc[mf][nf][r] + bv;
            }
        }
}

// ---------------------------------------------------------------------------
// Repack deltaB into MFMA-fragment order: frag f=(mf,t), lane l holds
// A[mf*16 + (l&15)][t*32 + (l>>4)*8 .. +7] as 16 contiguous bytes.
__global__ __launch_bounds__(256) void k_repack(const unsigned short* __restrict__ deltaB,
        unsigned short* __restrict__ Apack)
{
    int f = blockIdx.x * 4 + (threadIdx.x >> 6);   // 0..383 (12 mf * 32 t)
    int lane = threadIdx.x & 63;
    int mf = f >> 5, t = f & 31;
    int row = mf*16 + (lane & 15);
    int colk = t*32 + (lane >> 4)*8;
    int4 v = *(const int4*)(deltaB + (size_t)row*DD + colk);
    *(int4*)(Apack + ((size_t)f*64 + lane)*8) = v;
}

// ---------------------------------------------------------------------------
// Transpose-convert bowW f32[k=1024][n=54945] -> Bt bf16[n][k] (64x64 tiles)
__global__ __launch_bounds__(256) void k_cvt(const float* __restrict__ Bm,
        unsigned short* __restrict__ Bt)
{
    __shared__ unsigned short Ls[64][72];
    const int N = NVOCAB;
    int n0 = blockIdx.x * 64;
    int k0 = blockIdx.y * 64;
    int t = threadIdx.x;
    #pragma unroll
    for (int p = 0; p < 4; ++p) {
        int idx = p * 256 + t;
        int k = idx >> 4;              // 0..63
        int n = (idx & 15) * 4;        // 0..60
        int gn = n0 + n;
        const float* src = Bm + (size_t)(k0 + k) * N;
        float4 v;
        if (gn + 3 < N) v = *(const float4*)&src[gn];
        else {
            v.x = (gn   < N) ? src[gn  ] : 0.0f;
            v.y = (gn+1 < N) ? src[gn+1] : 0.0f;
            v.z = (gn+2 < N) ? src[gn+2] : 0.0f;
            v.w = (gn+3 < N) ? src[gn+3] : 0.0f;
        }
        Ls[n  ][k] = f2b(v.x);
        Ls[n+1][k] = f2b(v.y);
        Ls[n+2][k] = f2b(v.z);
        Ls[n+3][k] = f2b(v.w);
    }
    __syncthreads();
    #pragma unroll
    for (int p = 0; p < 2; ++p) {
        int idx = p * 256 + t;
        int n = idx >> 3;              // 0..63
        int ko = (idx & 7) * 8;        // 0..56
        if (n0 + n < N)
            *(int4*)&Bt[(size_t)(n0 + n) * DD + k0 + ko] = *(const int4*)&Ls[n][ko];
    }
}

// ---------------------------------------------------------------------------
// bow GEMM on transposed bf16 B: Apack[192,1024] @ Bt[n][k] -> C[192,54945].
// 256 thr / 4 waves; wave owns 48 rows (3 mf) x 64 cols (4 nf).
// B-frag = ONE contiguous 16B load/lane; each 128B line feeds 8 k-steps (L1
// reuse); Bt is L3-resident (just written by k_cvt). No LDS, no barriers.
__global__ __launch_bounds__(256) void mm_bowT(
        const unsigned short* __restrict__ Apack,
        const unsigned short* __restrict__ Bt,
        float* __restrict__ C)
{
    const int N = NVOCAB;
    int tid = threadIdx.x;
    int lane = tid & 63, wm = tid >> 6;
    int l16 = lane & 15, g = lane >> 4;
    int col0 = blockIdx.x * 64;

    const unsigned short* bp[4];
    #pragma unroll
    for (int nf = 0; nf < 4; ++nf) {
        int c = col0 + nf*16 + l16;
        bp[nf] = Bt + (size_t)((c < N) ? c : (N - 1)) * DD + g * 8;
    }
    const unsigned short* ap = Apack + ((size_t)(wm*3*32)*64 + lane) * 8;

    f32x4 acc[3][4] = {};
    bf16x8 bc0, bc1, bc2, bc3;
    bc0 = *(const bf16x8*)bp[0];
    bc1 = *(const bf16x8*)bp[1];
    bc2 = *(const bf16x8*)bp[2];
    bc3 = *(const bf16x8*)bp[3];

    #pragma unroll 4
    for (int t = 0; t < 32; ++t) {
        bf16x8 bn0, bn1, bn2, bn3;
        if (t < 31) {
            bn0 = *(const bf16x8*)(bp[0] + (t+1)*32);
            bn1 = *(const bf16x8*)(bp[1] + (t+1)*32);
            bn2 = *(const bf16x8*)(bp[2] + (t+1)*32);
            bn3 = *(const bf16x8*)(bp[3] + (t+1)*32);
        }
        #pragma unroll
        for (int j = 0; j < 3; ++j) {
            bf16x8 af = *(const bf16x8*)(ap + (size_t)((j*32 + t) * 64) * 8);
            acc[j][0] = __builtin_amdgcn_mfma_f32_16x16x32_bf16(af, bc0, acc[j][0], 0, 0, 0);
            acc[j][1] = __builtin_amdgcn_mfma_f32_16x16x32_bf16(af, bc1, acc[j][1], 0, 0, 0);
            acc[j][2] = __builtin_amdgcn_mfma_f32_16x16x32_bf16(af, bc2, acc[j][2], 0, 0, 0);
            acc[j][3] = __builtin_amdgcn_mfma_f32_16x16x32_bf16(af, bc3, acc[j][3], 0, 0, 0);
        }
        bc0 = bn0; bc1 = bn1; bc2 = bn2; bc3 = bn3;
    }
    #pragma unroll
    for (int j = 0; j < 3; ++j)
        #pragma unroll
        for (int nf = 0; nf < 4; ++nf) {
            int cc = col0 + nf*16 + l16;
            if (cc < N) {
                #pragma unroll
                for (int r = 0; r < 4; ++r) {
                    int rr = wm*48 + j*16 + g*4 + r;
                    C[(size_t)rr*N + cc] = acc[j][nf][r];
                }
            }
        }
}

// ---------------------------------------------------------------------------
// Fallback bow GEMM (no Bt workspace): Apack direct, B f32 column loads.
__global__ __launch_bounds__(256) void mm_bow(
        const unsigned short* __restrict__ Apack, const float* __restrict__ Bm,
        float* __restrict__ C)
{
    const int N = NVOCAB;
    int tid = threadIdx.x;
    int lane = tid & 63, wave = tid >> 6;
    int l16 = lane & 15, g = lane >> 4;
    int col = blockIdx.x * 64 + wave * 16 + l16;
    int colc = (col < N) ? col : (N - 1);
    const float* bbase = Bm + (size_t)(g * 8) * N + colc;
    const unsigned short* apack = Apack + (size_t)lane * 8;

    f32x4 acc[12] = {};
    float bA[8], bB[8];
    bf16x8 aX[12];
    for (int t = 0; t < 32; t += 1) {
        const float* bp = bbase + (size_t)t * 32 * N;
        #pragma unroll
        for (int j = 0; j < 8; ++j) bA[j] = bp[(size_t)j * N];
        bf16x8 fr;
        #pragma unroll
        for (int j = 0; j < 8; ++j) ((unsigned short*)&fr)[j] = f2b(bA[j]);
        #pragma unroll
        for (int mf = 0; mf < 12; ++mf) {
            bf16x8 af = *(const bf16x8*)(apack + ((size_t)(mf*32 + t) * 64) * 8);
            acc[mf] = __builtin_amdgcn_mfma_f32_16x16x32_bf16(af, fr, acc[mf], 0, 0, 0);
        }
    }
    if (col < N) {
        #pragma unroll
        for (int mf = 0; mf < 12; ++mf)
            #pragma unroll
            for (int r = 0; r < 4; ++r)
                C[(size_t)(mf * 16 + g * 4 + r) * N + col] = acc[mf][r];
    }
}

// ---------------------------------------------------------------------------
// Prefix counts of edge types along i, LDS-staged: cnt[b,i,k] = uint2 of 8 u8
__global__ __launch_bounds__(256) void k_cnt(const int* __restrict__ et, uint2* __restrict__ cnt)
{
    __shared__ unsigned char e_sh[TT*TT];
    int b = blockIdx.x, tid = threadIdx.x;
    for (int idx = tid; idx < (TT*TT)/4; idx += 256) {
        int4 v = ((const int4*)(et + (size_t)b*TT*TT))[idx];
        unsigned pk = (unsigned)v.x | ((unsigned)v.y << 8) | ((unsigned)v.z << 16) | ((unsigned)v.w << 24);
        *(unsigned*)&e_sh[idx*4] = pk;
    }
    __syncthreads();
    int k = tid;
    if (k < TT) {
        unsigned lo = 0, hi = 0;
        for (int i = 0; i < TT; ++i) {
            int r = e_sh[i*TT + k];
            if (r < 4) lo += 1u << (8*r); else hi += 1u << (8*(r-4));
            cnt[((size_t)b*TT + i)*TT + k] = make_uint2(lo, hi);
        }
    }
}

// ---------------------------------------------------------------------------
// Fully fused attention per (b,h,half): prep (A=Q+S_diag, AR) + scores +
// softmax + PV. Grid B*H*2 = 256 blocks, 512 thr (8 waves), 36 rows/block.
__global__ __launch_bounds__(512) void k_attn(const float* __restrict__ Qb,
        const float* __restrict__ Kg, const float* __restrict__ Vg,
        const uint2* __restrict__ cnt, const float* __restrict__ rel,
        const int* __restrict__ mask, float* __restrict__ out)
{
    int bid = blockIdx.x;
    int is = bid & 1;
    int h  = (bid >> 1) & (HH-1);
    int b  = bid >> 5;
    __shared__ float K_sh[DH][TT+1];    // transposed [d][t]
    __shared__ float V_sh[TT][DH+4];    // row-major, pad 4 (16B-aligned rows)
    __shared__ float rel_sh[8][DH];
    __shared__ float a_row[8][DH];
    __shared__ float p_row[8][TT];
    int tid = threadIdx.x;
    int lane = tid & 63, w = tid >> 6;

    // stage K (transposed), V, rel
    for (int idx = tid; idx < TT*16; idx += 512) {
        int r = idx >> 4, q4 = (idx & 15) * 4;
        size_t goff = ((size_t)(b*TT + r))*DD + h*DH + q4;
        float4 kv = *(const float4*)&Kg[goff];
        K_sh[q4  ][r] = kv.x; K_sh[q4+1][r] = kv.y;
        K_sh[q4+2][r] = kv.z; K_sh[q4+3][r] = kv.w;
        float4 vv = *(const float4*)&Vg[goff];
        *(float4*)&V_sh[r][q4] = vv;
    }
    if (tid < 128) {
        int r = tid >> 4, q4 = (tid & 15) * 4;
        *(float4*)&rel_sh[r][q4] = *(const float4*)&rel[r*DD + h*DH + q4];
    }
    __syncthreads();

    for (int ii = w; ii < TT/2; ii += 8) {
        int i = is*(TT/2) + ii;
        size_t rowoff = (size_t)(b*TT + i);
        // --- prep: a = q + sum_r cr[r]*rel_r ; AR[r] = <a, rel_r>
        float q = Qb[rowoff*DD + h*DH + lane];
        float crd[8]; dec8(cnt[rowoff*TT + i], crd);
        float a = q;
        #pragma unroll
        for (int r = 0; r < 8; ++r) a += crd[r]*rel_sh[r][lane];
        a_row[w][lane] = a;
        float arr[8];
        #pragma unroll
        for (int r = 0; r < 8; ++r) {
            float pr = a * rel_sh[r][lane];
            #pragma unroll
            for (int off = 32; off; off >>= 1) pr += __shfl_xor(pr, off);
            arr[r] = pr;
        }
        // --- scores: pass1 key t=lane, pass2 key t=64+lane (lane<8)
        float s1;
        {
            int t = lane;
            float s = 0.0f;
            #pragma unroll
            for (int d0 = 0; d0 < DH; d0 += 4) {
                float4 av = *(const float4*)&a_row[w][d0];
                s += av.x*K_sh[d0][t] + av.y*K_sh[d0+1][t]
                   + av.z*K_sh[d0+2][t] + av.w*K_sh[d0+3][t];
            }
            float cr2[8]; dec8(cnt[rowoff*TT + t], cr2);
            float s2v = cr2[0]*arr[0] + cr2[1]*arr[1] + cr2[2]*arr[2] + cr2[3]*arr[3]
                      + cr2[4]*arr[4] + cr2[5]*arr[5] + cr2[6]*arr[6] + cr2[7]*arr[7];
            int m = mask[rowoff*TT + t];
            s1 = (m == 0) ? -1e9f : (s + s2v)*0.125f;
        }
        float s2 = -1e30f;
        if (lane < TT - DH) {
            int t = DH + lane;
            float s = 0.0f;
            #pragma unroll
            for (int d0 = 0; d0 < DH; d0 += 4) {
                float4 av = *(const float4*)&a_row[w][d0];
                s += av.x*K_sh[d0][t] + av.y*K_sh[d0+1][t]
                   + av.z*K_sh[d0+2][t] + av.w*K_sh[d0+3][t];
            }
            float cr2[8]; dec8(cnt[rowoff*TT + t], cr2);
            float s2v = cr2[0]*arr[0] + cr2[1]*arr[1] + cr2[2]*arr[2] + cr2[3]*arr[3]
                      + cr2[4]*arr[4] + cr2[5]*arr[5] + cr2[6]*arr[6] + cr2[7]*arr[7];
            int m = mask[rowoff*TT + t];
            s2 = (m == 0) ? -1e9f : (s + s2v)*0.125f;
        }
        // --- softmax over 72
        float mx = fmaxf(s1, s2);
        #pragma unroll
        for (int off = 32; off; off >>= 1) mx = fmaxf(mx, __shfl_xor(mx, off));
        float e1 = __expf(s1 - mx);
        float e2 = (lane < TT - DH) ? __expf(s2 - mx) : 0.0f;
        float sm = e1 + e2;
        #pragma unroll
        for (int off = 32; off; off >>= 1) sm += __shfl_xor(sm, off);
        float inv = 1.0f / sm;
        p_row[w][lane] = e1 * inv;
        if (lane < TT - DH) p_row[w][DH + lane] = e2 * inv;
        // --- PV: lane owns d = lane
        float o = 0.0f;
        #pragma unroll 8
        for (int t = 0; t < TT; ++t) o += p_row[w][t] * V_sh[t][lane];
        out[rowoff*DD + h*DH + lane] = o;
    }
}

// ---------------------------------------------------------------------------
// Merged epilogue: output splits + delta(bf16) + strategy/emotion logits
__global__ __launch_bounds__(256) void k_finlog(const float* __restrict__ outs,
        const float* __restrict__ sem_cls,
        const float* __restrict__ strW, const float* __restrict__ strB,
        const float* __restrict__ emoW, const float* __restrict__ emoB,
        float* __restrict__ o_last_stra, float* __restrict__ o_emo,
        float* __restrict__ o_last_delta, float* __restrict__ o_str,
        float* __restrict__ o_emo_log, unsigned short* __restrict__ deltaB)
{
    __shared__ float part[14][16];
    int bid = blockIdx.x; int b = bid / UU, u = bid % UU;
    const float* sem = outs + ((size_t)(b*TT + 3*u))*DD;
    const float* st  = sem + DD;
    const float* em  = st + DD;
    const float* sc  = sem_cls + ((size_t)(b*UU + u))*DD;
    unsigned short* de = deltaB + ((size_t)(b*UU + u))*DD;
    float* oe = o_emo + ((size_t)(b*UU + u))*DD;
    int t = threadIdx.x;
    for (int d = t; d < DD; d += 256) {
        float dl = sem[d] - sc[d];
        de[d] = f2b(dl); oe[d] = em[d];
        if (u == UU-1) { o_last_stra[b*DD + d] = st[d]; o_last_delta[b*DD + d] = dl; }
    }
    if (t < 224) {
        int o = t >> 4, c = t & 15;
        float s = 0.0f;
        if (o < 8) {
            for (int d = c*64; d < c*64 + 64; ++d) s += st[d]*strW[d*8 + o];
        } else {
            int j = o - 8;
            for (int d = c*64; d < c*64 + 64; ++d) s += em[d]*emoW[d*6 + j];
        }
        part[o][c] = s;
    }
    __syncthreads();
    if (t < 14) {
        float s = 0.0f;
        #pragma unroll
        for (int c2 = 0; c2 < 16; ++c2) s += part[t][c2];
        if (t < 8) o_str[(b*UU + u)*8 + t] = s + strB[t];
        else       o_emo_log[(b*UU + u)*6 + (t-8)] = s + emoB[t-8];
    }
}

// ---------------------------------------------------------------------------
extern "C" void kernel_launch(void* const* d_in, const int* in_sizes, int n_in,
                              void* d_out, int out_size, void* d_ws, size_t ws_size,
                              hipStream_t stream)
{
    const float* hidden  = (const float*)d_in[0];
    const float* emo_csk = (const float*)d_in[1];
    const float* Wq  = (const float*)d_in[2];
    const float* bq  = (const float*)d_in[3];
    const float* Wk  = (const float*)d_in[4];
    const float* bk  = (const float*)d_in[5];
    const float* Wv  = (const float*)d_in[6];
    const float* bv  = (const float*)d_in[7];
    const float* rel = (const float*)d_in[8];
    const float* fusW = (const float*)d_in[9];
    const float* fusB = (const float*)d_in[10];
    const float* bng = (const float*)d_in[11];
    const float* bnb = (const float*)d_in[12];
    const float* bnm = (const float*)d_in[13];
    const float* bnv = (const float*)d_in[14];
    const float* cskW = (const float*)d_in[15];
    const float* cskB = (const float*)d_in[16];
    const float* emoW = (const float*)d_in[17];
    const float* emoB = (const float*)d_in[18];
    const float* strW = (const float*)d_in[19];
    const float* strB = (const float*)d_in[20];
    const float* bowW = (const float*)d_in[21];
    const int* clsIdx = (const int*)d_in[22];
    const int* tGraph = (const int*)d_in[23];
    const int* iGraph = (const int*)d_in[24];
    const int* tEdge  = (const int*)d_in[25];
    const int* iEdge  = (const int*)d_in[26];

    float* out = (float*)d_out;
    float* o_last_stra  = out;             // B*D          = 8192
    float* o_emo_trans  = out + 8192;      // B*U*D        = 196608
    float* o_last_delta = out + 204800;    // B*D          = 8192
    float* o_sem_cls    = out + 212992;    // B*U*D        = 196608
    float* o_str_log    = out + 409600;    // B*U*8        = 1536
    float* o_emo_log    = out + 411136;    // B*U*6        = 1152
    float* o_bow        = out + 412288;    // B*U*VOCAB

    float* ws = (float*)d_ws;
    const int SZ_BTD = BB*TT*DD;   // 589824
    const int SZ_BUD = BB*UU*DD;   // 196608
    float* trans_in  = ws;
    float* Qb        = trans_in + SZ_BTD;
    float* Kb        = Qb + SZ_BTD;
    float* Vb        = Kb + SZ_BTD;
    float* trans_out = Vb + SZ_BTD;
    float* inter_out = trans_out + SZ_BTD;
    float* outsB     = inter_out + SZ_BTD;
    float* csk_norm  = outsB + SZ_BTD;
    float* cnt_f     = csk_norm + SZ_BUD;
    uint2* cntb      = (uint2*)cnt_f;                  // B*T*T uint2
    unsigned short* deltaB = (unsigned short*)(cnt_f + BB*TT*TT*2);
    unsigned short* Apack  = deltaB + SZ_BUD;          // 192*1024 bf16 frag-order
    unsigned short* Bt     = Apack + SZ_BUD;           // 54945*1024 bf16 transposed
    size_t need = (size_t)((char*)(Bt + (size_t)NVOCAB*DD) - (char*)d_ws);
    bool has_bt = (ws_size >= need);

    // 1. gather cls + build trans_in; write sem_cls_embs
    k_gather_cls<<<dim3(BB*UU), dim3(256), 0, stream>>>(hidden, clsIdx, o_sem_cls, trans_in);
    // 2. batchnorm
    int nbn = BB*UU*CSKN;
    k_bn<<<dim3((nbn+255)/256), dim3(256), 0, stream>>>(emo_csk, bng, bnb, bnm, bnv, csk_norm, nbn);
    // 3. csk_proj GEMM fused with scatter-add into trans_in[:,2::3]
    mm64<4><<<dim3(16, 3), dim3(256), 0, stream>>>(csk_norm, nullptr, CSKN, cskW, cskB,
            nullptr, nullptr, trans_in, DD, CSKN);

    auto attention = [&](const float* x, const int* graph, const int* edge, float* ctx_out) {
        mm_qkv<<<dim3(24, (BB*TT)/64), dim3(256), 0, stream>>>(x, Wq, Wk, Wv, bq, bk, bv, Qb, Kb, Vb);
        k_cnt<<<dim3(BB), dim3(256), 0, stream>>>(edge, cntb);
        k_attn<<<dim3(BB*HH*2), dim3(512), 0, stream>>>(Qb, Kb, Vb, cntb, rel, graph, ctx_out);
    };
    attention(trans_in, tGraph, tEdge, trans_out);
    attention(trans_out, iGraph, iEdge, inter_out);

    // fusion gate + blend fused: outsB = g*trans + (1-g)*inter
    mm64<3><<<dim3(16, (BB*TT)/64), dim3(256), 0, stream>>>(trans_out, inter_out, DD, fusW, fusB,
            trans_out, inter_out, outsB, DD, 2*DD);

    // merged epilogue (writes deltaB bf16 + small logits)
    k_finlog<<<dim3(BB*UU), dim3(256), 0, stream>>>(outsB, o_sem_cls, strW, strB, emoW, emoB,
            o_last_stra, o_emo_trans, o_last_delta, o_str_log, o_emo_log, deltaB);

    // bow path: transpose-convert bowW to bf16 Bt (L3-resident), then GEMM
    k_repack<<<dim3(96), dim3(256), 0, stream>>>(deltaB, Apack);
    if (has_bt) {
        k_cvt<<<dim3((NVOCAB+63)/64, 16), dim3(256), 0, stream>>>(bowW, Bt);
        mm_bowT<<<dim3((NVOCAB+63)/64), dim3(256), 0, stream>>>(Apack, Bt, o_bow);
    } else {
        mm_bow<<<dim3((NVOCAB+63)/64), dim3(256), 0, stream>>>(Apack, bowW, o_bow);
    }
}

// Round 11
// 324.978 us; speedup vs baseline: 1.2036x; 1.2036x over previous
//
#include <hip/hip_runtime.h>
#include <math.h>

// Problem constants
#define BB 8
#define LL 512
#define UU 24
#define DD 1024
#define HH 16
#define DH 64
#define TT 72
#define CSKN 1024
#define NVOCAB 54945

typedef __attribute__((ext_vector_type(8))) short bf16x8;
typedef __attribute__((ext_vector_type(4))) float f32x4;

__device__ inline unsigned short f2b(float x) {
    unsigned u = __float_as_uint(x);
    unsigned r = u + 0x7FFFu + ((u >> 16) & 1u);
    return (unsigned short)(r >> 16);
}
__device__ inline unsigned pack2(float lo, float hi) {
    return (unsigned)f2b(lo) | ((unsigned)f2b(hi) << 16);
}
__device__ inline void dec8(uint2 c, float* cr) {
    cr[0] = (float)( c.x        & 0xff); cr[1] = (float)((c.x >>  8) & 0xff);
    cr[2] = (float)((c.x >> 16) & 0xff); cr[3] = (float)((c.x >> 24) & 0xff);
    cr[4] = (float)( c.y        & 0xff); cr[5] = (float)((c.y >>  8) & 0xff);
    cr[6] = (float)((c.y >> 16) & 0xff); cr[7] = (float)((c.y >> 24) & 0xff);
}

// ---------------------------------------------------------------------------
// Merged: gather cls (blocks 0..191) + batchnorm (blocks 192..959)
__global__ __launch_bounds__(256) void k_gather_bn(const float* __restrict__ hidden,
        const int* __restrict__ idx, float* __restrict__ sem_cls, float* __restrict__ trans_in,
        const float* __restrict__ x, const float* __restrict__ g,
        const float* __restrict__ be, const float* __restrict__ mu,
        const float* __restrict__ var, float* __restrict__ y)
{
    int bid = blockIdx.x;
    if (bid < BB*UU) {
        int b = bid / UU, u = bid % UU;
        int row = idx[b*UU + u];
        const float* src = hidden + ((size_t)(b*LL + row))*DD;
        float* d0 = trans_in + ((size_t)(b*TT + 3*u))*DD;
        float* sc = sem_cls + ((size_t)(b*UU + u))*DD;
        for (int d = threadIdx.x; d < DD; d += 256) {
            float v = src[d];
            sc[d] = v;
            d0[d] = v; d0[DD + d] = v; d0[2*DD + d] = v;
        }
    } else {
        int i = (bid - BB*UU)*256 + threadIdx.x;
        int n = BB*UU*CSKN;
        if (i < n) {
            int c = i % CSKN;
            y[i] = (x[i] - mu[c]) * (1.0f/sqrtf(var[c] + 1e-5f)) * g[c] + be[c];
        }
    }
}

// ---------------------------------------------------------------------------
// Double-buffered MFMA bf16 GEMM, 64x64 tile, 256 thr, 4 waves (2x2).
// EPI: 3 = gate-blend C=g*ep1+(1-g)*ep2, g=sigmoid(A@B+bias)
//      4 = csk: trans_in[b*72+3u+2][cc] += (A@B+bias), skip u==U-1 (C=trans_in)
template<int EPI>
__global__ __launch_bounds__(256) void mm64(
        const float* __restrict__ A1, const float* __restrict__ A2, int K1,
        const float* __restrict__ Bm, const float* __restrict__ bias,
        const float* __restrict__ ep1, const float* __restrict__ ep2,
        float* __restrict__ C, int N, int K)
{
    __shared__ __align__(16) unsigned short As[2][64][40];
    __shared__ __align__(16) unsigned short Bs[2][64][40];
    int tid = threadIdx.x;
    int wave = tid >> 6, lane = tid & 63;
    int l16 = lane & 15, g = lane >> 4;
    int wm = wave & 1, wn = wave >> 1;
    int row0 = blockIdx.y * 64, col0 = blockIdx.x * 64;

    int ar = tid >> 2, akq = (tid & 3) * 8;
    int bj0 = (tid & 31) * 2, bk0 = (tid >> 5) * 2;
    float4 a0, a1;
    float2 q00, q01, q10, q11;

    auto loadT = [&](int k0) {
        int kk = k0 + akq;
        const float* src = (kk < K1) ? A1 + (size_t)(row0+ar)*K1 + kk
                                     : A2 + (size_t)(row0+ar)*(K-K1) + (kk-K1);
        a0 = *(const float4*)src; a1 = *(const float4*)(src+4);
        const float* bs0 = Bm + (size_t)(k0 + bk0)*N + col0 + bj0;
        q00 = *(const float2*)bs0;       q01 = *(const float2*)(bs0 + N);
        const float* bs1 = bs0 + (size_t)16*N;
        q10 = *(const float2*)bs1;       q11 = *(const float2*)(bs1 + N);
    };
    auto storeT = [&](int buf) {
        unsigned* da = (unsigned*)&As[buf][ar][akq];
        da[0] = pack2(a0.x, a0.y); da[1] = pack2(a0.z, a0.w);
        da[2] = pack2(a1.x, a1.y); da[3] = pack2(a1.z, a1.w);
        *(unsigned*)&Bs[buf][bj0  ][bk0]    = pack2(q00.x, q01.x);
        *(unsigned*)&Bs[buf][bj0+1][bk0]    = pack2(q00.y, q01.y);
        *(unsigned*)&Bs[buf][bj0  ][bk0+16] = pack2(q10.x, q11.x);
        *(unsigned*)&Bs[buf][bj0+1][bk0+16] = pack2(q10.y, q11.y);
    };

    f32x4 acc[2][2] = {};
    loadT(0); storeT(0);
    __syncthreads();
    int nt = K / 32;
    for (int t = 0; t < nt; ++t) {
        int cur = t & 1;
        if (t + 1 < nt) loadT((t+1)*32);
        bf16x8 af[2], bfr[2];
        #pragma unroll
        for (int mf = 0; mf < 2; ++mf) af[mf] = *(const bf16x8*)&As[cur][wm*32 + mf*16 + l16][g*8];
        #pragma unroll
        for (int nf = 0; nf < 2; ++nf) bfr[nf] = *(const bf16x8*)&Bs[cur][wn*32 + nf*16 + l16][g*8];
        #pragma unroll
        for (int mf = 0; mf < 2; ++mf)
            #pragma unroll
            for (int nf = 0; nf < 2; ++nf)
                acc[mf][nf] = __builtin_amdgcn_mfma_f32_16x16x32_bf16(af[mf], bfr[nf], acc[mf][nf], 0, 0, 0);
        if (t + 1 < nt) storeT(cur ^ 1);
        __syncthreads();
    }
    #pragma unroll
    for (int mf = 0; mf < 2; ++mf)
        #pragma unroll
        for (int nf = 0; nf < 2; ++nf) {
            int cc = col0 + wn*32 + nf*16 + l16;
            float bv = bias[cc];
            #pragma unroll
            for (int r = 0; r < 4; ++r) {
                int rr = row0 + wm*32 + mf*16 + g*4 + r;
                float v = acc[mf][nf][r] + bv;
                if (EPI == 3) {
                    float gg = 1.0f/(1.0f + __expf(-v));
                    float tv = ep1[(size_t)rr*N + cc];
                    float iv = ep2[(size_t)rr*N + cc];
                    C[(size_t)rr*N + cc] = gg*tv + (1.0f - gg)*iv;
                } else { // EPI == 4
                    int bq = rr / UU, uq = rr % UU;
                    if (uq < UU-1) {
                        float* dst = &C[((size_t)(bq*TT + 3*uq + 2))*DD + cc];
                        *dst += v;
                    }
                }
            }
        }
}

// ---------------------------------------------------------------------------
// Fused Q/K/V projection, BM=64 BN=128, dbuf. Grid (24, 9); blockIdx.x>>3 selects.
__global__ __launch_bounds__(256) void mm_qkv(
        const float* __restrict__ x,
        const float* __restrict__ W0, const float* __restrict__ W1, const float* __restrict__ W2,
        const float* __restrict__ v0, const float* __restrict__ v1, const float* __restrict__ v2,
        float* __restrict__ C0, float* __restrict__ C1, float* __restrict__ C2)
{
    __shared__ __align__(16) unsigned short As[2][64][40];
    __shared__ __align__(16) unsigned short Bs[2][128][40];
    int which = blockIdx.x >> 3;
    int col0 = (blockIdx.x & 7) * 128;
    int row0 = blockIdx.y * 64;
    const float* W  = (which == 0) ? W0 : (which == 1) ? W1 : W2;
    const float* bb = (which == 0) ? v0 : (which == 1) ? v1 : v2;
    float*       C  = (which == 0) ? C0 : (which == 1) ? C1 : C2;
    int tid = threadIdx.x;
    int wave = tid >> 6, lane = tid & 63;
    int l16 = lane & 15, g = lane >> 4;
    int wm = wave & 1, wn = wave >> 1;

    int ar = tid >> 2, akq = (tid & 3) * 8;
    int bj0 = (tid & 63) * 2, ks = tid >> 6;   // 4 k-pair slots per thread
    float4 a0, a1;
    float2 b0[4], b1[4];

    auto loadT = [&](int k0) {
        const float* src = x + (size_t)(row0+ar)*DD + k0 + akq;
        a0 = *(const float4*)src; a1 = *(const float4*)(src+4);
        #pragma unroll
        for (int s = 0; s < 4; ++s) {
            int kb = (ks + 4*s)*2;
            const float* bp = W + (size_t)(k0 + kb)*DD + col0 + bj0;
            b0[s] = *(const float2*)bp;
            b1[s] = *(const float2*)(bp + DD);
        }
    };
    auto storeT = [&](int buf) {
        unsigned* da = (unsigned*)&As[buf][ar][akq];
        da[0] = pack2(a0.x, a0.y); da[1] = pack2(a0.z, a0.w);
        da[2] = pack2(a1.x, a1.y); da[3] = pack2(a1.z, a1.w);
        #pragma unroll
        for (int s = 0; s < 4; ++s) {
            int kb = (ks + 4*s)*2;
            *(unsigned*)&Bs[buf][bj0  ][kb] = pack2(b0[s].x, b1[s].x);
            *(unsigned*)&Bs[buf][bj0+1][kb] = pack2(b0[s].y, b1[s].y);
        }
    };

    f32x4 acc[2][4] = {};
    loadT(0); storeT(0);
    __syncthreads();
    for (int t = 0; t < 32; ++t) {
        int cur = t & 1;
        if (t < 31) loadT((t+1)*32);
        bf16x8 af[2], bfr[4];
        #pragma unroll
        for (int mf = 0; mf < 2; ++mf) af[mf] = *(const bf16x8*)&As[cur][wm*32 + mf*16 + l16][g*8];
        #pragma unroll
        for (int nf = 0; nf < 4; ++nf) bfr[nf] = *(const bf16x8*)&Bs[cur][wn*64 + nf*16 + l16][g*8];
        #pragma unroll
        for (int mf = 0; mf < 2; ++mf)
            #pragma unroll
            for (int nf = 0; nf < 4; ++nf)
                acc[mf][nf] = __builtin_amdgcn_mfma_f32_16x16x32_bf16(af[mf], bfr[nf], acc[mf][nf], 0, 0, 0);
        if (t < 31) storeT(cur ^ 1);
        __syncthreads();
    }
    #pragma unroll
    for (int mf = 0; mf < 2; ++mf)
        #pragma unroll
        for (int nf = 0; nf < 4; ++nf) {
            int cc = col0 + wn*64 + nf*16 + l16;
            float bv = bb[cc];
            #pragma unroll
            for (int r = 0; r < 4; ++r) {
                int rr = row0 + wm*32 + mf*16 + g*4 + r;
                C[(size_t)rr*DD + cc] = acc[mf][nf][r] + bv;
            }
        }
}

// ---------------------------------------------------------------------------
// bow GEMM (R6 best-measured variant): deltaB(bf16)[192,1024] @ bowW -> o_bow.
// 256 thr / 4 waves; wave owns 16 cols; B-fragments direct from global with
// a 4-deep register prefetch pipeline; A staged via LDS double-buffer.
__global__ __launch_bounds__(256) void mm_bow(
        const unsigned short* __restrict__ Ab, const float* __restrict__ Bm,
        float* __restrict__ C)
{
    __shared__ __align__(16) unsigned short A_lds[2][192][40];
    const int N = NVOCAB;
    int tid = threadIdx.x;
    int lane = tid & 63, wave = tid >> 6;
    int l16 = lane & 15, g = lane >> 4;
    int col = blockIdx.x * 64 + wave * 16 + l16;
    int colc = (col < N) ? col : (N - 1);
    const float* bbase = Bm + (size_t)(g * 8) * N + colc;

    int r0 = tid >> 2,          q0 = (tid & 3) * 8;
    int r1 = (tid + 256) >> 2,  q1 = ((tid + 256) & 3) * 8;
    int r2 = (tid + 512) >> 2,  q2 = ((tid + 512) & 3) * 8;

    auto loadAs = [&](int ks, int4& x0, int4& x1, int4& x2) {
        int k0 = ks * 32;
        x0 = *(const int4*)(Ab + (size_t)r0 * DD + k0 + q0);
        x1 = *(const int4*)(Ab + (size_t)r1 * DD + k0 + q1);
        x2 = *(const int4*)(Ab + (size_t)r2 * DD + k0 + q2);
    };
    auto writeAs = [&](int buf, int4 x0, int4 x1, int4 x2) {
        *(int4*)&A_lds[buf][r0][q0] = x0;
        *(int4*)&A_lds[buf][r1][q1] = x1;
        *(int4*)&A_lds[buf][r2][q2] = x2;
    };

    f32x4 acc[12] = {};
    float bs[4][8];
    int4 eA0, eA1, eA2, oA0, oA1, oA2;

#define LOADB(dst, t_) { const float* bp = bbase + (size_t)(t_) * 32 * N;      \
        _Pragma("unroll") for (int j = 0; j < 8; ++j) dst[j] = bp[(size_t)j * N]; }
#define PACKB(fr, sv) { _Pragma("unroll") for (int j = 0; j < 8; ++j)          \
        ((unsigned short*)&fr)[j] = f2b(sv[j]); }
#define MFMA12(buf, fr) { _Pragma("unroll") for (int mf = 0; mf < 12; ++mf) {  \
        bf16x8 af = *(const bf16x8*)&A_lds[buf][mf * 16 + l16][g * 8];         \
        acc[mf] = __builtin_amdgcn_mfma_f32_16x16x32_bf16(af, fr, acc[mf], 0, 0, 0); } }

    loadAs(0, eA0, eA1, eA2); writeAs(0, eA0, eA1, eA2);
    loadAs(1, oA0, oA1, oA2); writeAs(1, oA0, oA1, oA2);
    loadAs(2, eA0, eA1, eA2);
    #pragma unroll
    for (int p = 0; p < 4; ++p) LOADB(bs[p], p);
    __syncthreads();

    for (int t = 0; t < 32; t += 4) {
        #pragma unroll
        for (int p = 0; p < 4; ++p) {
            int P = t + p;
            bf16x8 fr;
            PACKB(fr, bs[p]);
            if (P + 4 < 32) LOADB(bs[p], P + 4);
            MFMA12(p & 1, fr);
            __syncthreads();
            if ((p & 1) == 0) {
                if (P + 2 < 32) writeAs(0, eA0, eA1, eA2);
                if (P + 3 < 32) loadAs(P + 3, oA0, oA1, oA2);
            } else {
                if (P + 2 < 32) writeAs(1, oA0, oA1, oA2);
                if (P + 3 < 32) loadAs(P + 3, eA0, eA1, eA2);
            }
        }
    }
#undef LOADB
#undef PACKB
#undef MFMA12
    if (col < N) {
        #pragma unroll
        for (int mf = 0; mf < 12; ++mf)
            #pragma unroll
            for (int r = 0; r < 4; ++r)
                C[(size_t)(mf * 16 + g * 4 + r) * N + col] = acc[mf][r];
    }
}

// ---------------------------------------------------------------------------
// Fully fused attention per (b,h,half): edge prefix (cnt) computed IN-BLOCK,
// prep (A=Q+S_diag, AR) + scores + softmax + PV. Grid B*H*2 = 256 blocks,
// 512 thr (8 waves), 36 rows/block. LDS = 62.8 KB.
__global__ __launch_bounds__(512) void k_attn(const float* __restrict__ Qb,
        const float* __restrict__ Kg, const float* __restrict__ Vg,
        const int* __restrict__ et, const float* __restrict__ rel,
        const int* __restrict__ mask, float* __restrict__ out)
{
    int bid = blockIdx.x;
    int is = bid & 1;
    int h  = (bid >> 1) & (HH-1);
    int b  = bid >> 5;
    int lo = is * (TT/2);
    __shared__ float K_sh[DH][TT+1];          // 18688 B, transposed [d][t]
    __shared__ float V_sh[TT][DH];            // 18432 B, row-major
    __shared__ uint2 cnt_sh[TT/2][TT];        // 20736 B, prefix counts rows [lo,lo+36)
    __shared__ __align__(16) unsigned char un_raw[6400];  // e_sh then rel/a/p
    float (*rel_sh)[DH] = (float(*)[DH])un_raw;           // [8][64]
    float (*a_row)[DH]  = (float(*)[DH])(un_raw + 2048);  // [8][64]
    float (*p_row)[TT]  = (float(*)[TT])(un_raw + 4096);  // [8][72]
    unsigned char* e_sh = un_raw;                          // [5184]
    int tid = threadIdx.x;
    int lane = tid & 63, w = tid >> 6;

    // stage K (transposed) and V
    for (int idx = tid; idx < TT*16; idx += 512) {
        int r = idx >> 4, q4 = (idx & 15) * 4;
        size_t goff = ((size_t)(b*TT + r))*DD + h*DH + q4;
        float4 kv = *(const float4*)&Kg[goff];
        K_sh[q4  ][r] = kv.x; K_sh[q4+1][r] = kv.y;
        K_sh[q4+2][r] = kv.z; K_sh[q4+3][r] = kv.w;
        float4 vv = *(const float4*)&Vg[goff];
        *(float4*)&V_sh[r][q4] = vv;
    }
    // stage edge types (packed u8) into union region
    for (int idx = tid; idx < (TT*TT)/4; idx += 512) {
        int4 v = ((const int4*)(et + (size_t)b*TT*TT))[idx];
        unsigned pk = (unsigned)v.x | ((unsigned)v.y << 8) | ((unsigned)v.z << 16) | ((unsigned)v.w << 24);
        *(unsigned*)&e_sh[idx*4] = pk;
    }
    __syncthreads();
    // in-block prefix counts along i for this half's rows
    if (tid < TT) {
        unsigned lo32 = 0, hi32 = 0;
        int iend = lo + TT/2;
        for (int i = 0; i < iend; ++i) {
            int r = e_sh[i*TT + tid];
            if (r < 4) lo32 += 1u << (8*r); else hi32 += 1u << (8*(r-4));
            if (i >= lo) cnt_sh[i - lo][tid] = make_uint2(lo32, hi32);
        }
    }
    __syncthreads();
    // load rel into union region (e_sh no longer needed)
    if (tid < 128) {
        int r = tid >> 4, q4 = (tid & 15) * 4;
        *(float4*)&rel_sh[r][q4] = *(const float4*)&rel[r*DD + h*DH + q4];
    }
    __syncthreads();

    for (int ii = w; ii < TT/2; ii += 8) {
        int i = lo + ii;
        size_t rowoff = (size_t)(b*TT + i);
        // --- prep: a = q + sum_r cr[r]*rel_r ; AR[r] = <a, rel_r>
        float q = Qb[rowoff*DD + h*DH + lane];
        float crd[8]; dec8(cnt_sh[ii][i], crd);
        float a = q;
        #pragma unroll
        for (int r = 0; r < 8; ++r) a += crd[r]*rel_sh[r][lane];
        a_row[w][lane] = a;
        float arr[8];
        #pragma unroll
        for (int r = 0; r < 8; ++r) {
            float pr = a * rel_sh[r][lane];
            #pragma unroll
            for (int off = 32; off; off >>= 1) pr += __shfl_xor(pr, off);
            arr[r] = pr;
        }
        // --- scores: pass1 key t=lane, pass2 key t=64+lane (lane<8)
        float s1;
        {
            int t = lane;
            float s = 0.0f;
            #pragma unroll
            for (int d0 = 0; d0 < DH; d0 += 4) {
                float4 av = *(const float4*)&a_row[w][d0];
                s += av.x*K_sh[d0][t] + av.y*K_sh[d0+1][t]
                   + av.z*K_sh[d0+2][t] + av.w*K_sh[d0+3][t];
            }
            float cr2[8]; dec8(cnt_sh[ii][t], cr2);
            float s2v = cr2[0]*arr[0] + cr2[1]*arr[1] + cr2[2]*arr[2] + cr2[3]*arr[3]
                      + cr2[4]*arr[4] + cr2[5]*arr[5] + cr2[6]*arr[6] + cr2[7]*arr[7];
            int m = mask[rowoff*TT + t];
            s1 = (m == 0) ? -1e9f : (s + s2v)*0.125f;
        }
        float s2 = -1e30f;
        if (lane < TT - DH) {
            int t = DH + lane;
            float s = 0.0f;
            #pragma unroll
            for (int d0 = 0; d0 < DH; d0 += 4) {
                float4 av = *(const float4*)&a_row[w][d0];
                s += av.x*K_sh[d0][t] + av.y*K_sh[d0+1][t]
                   + av.z*K_sh[d0+2][t] + av.w*K_sh[d0+3][t];
            }
            float cr2[8]; dec8(cnt_sh[ii][t], cr2);
            float s2v = cr2[0]*arr[0] + cr2[1]*arr[1] + cr2[2]*arr[2] + cr2[3]*arr[3]
                      + cr2[4]*arr[4] + cr2[5]*arr[5] + cr2[6]*arr[6] + cr2[7]*arr[7];
            int m = mask[rowoff*TT + t];
            s2 = (m == 0) ? -1e9f : (s + s2v)*0.125f;
        }
        // --- softmax over 72
        float mx = fmaxf(s1, s2);
        #pragma unroll
        for (int off = 32; off; off >>= 1) mx = fmaxf(mx, __shfl_xor(mx, off));
        float e1 = __expf(s1 - mx);
        float e2 = (lane < TT - DH) ? __expf(s2 - mx) : 0.0f;
        float sm = e1 + e2;
        #pragma unroll
        for (int off = 32; off; off >>= 1) sm += __shfl_xor(sm, off);
        float inv = 1.0f / sm;
        p_row[w][lane] = e1 * inv;
        if (lane < TT - DH) p_row[w][DH + lane] = e2 * inv;
        // --- PV: lane owns d = lane
        float o = 0.0f;
        #pragma unroll 8
        for (int t = 0; t < TT; ++t) o += p_row[w][t] * V_sh[t][lane];
        out[rowoff*DD + h*DH + lane] = o;
    }
}

// ---------------------------------------------------------------------------
// Merged epilogue: output splits + delta(bf16) + strategy/emotion logits
__global__ __launch_bounds__(256) void k_finlog(const float* __restrict__ outs,
        const float* __restrict__ sem_cls,
        const float* __restrict__ strW, const float* __restrict__ strB,
        const float* __restrict__ emoW, const float* __restrict__ emoB,
        float* __restrict__ o_last_stra, float* __restrict__ o_emo,
        float* __restrict__ o_last_delta, float* __restrict__ o_str,
        float* __restrict__ o_emo_log, unsigned short* __restrict__ deltaB)
{
    __shared__ float part[14][16];
    int bid = blockIdx.x; int b = bid / UU, u = bid % UU;
    const float* sem = outs + ((size_t)(b*TT + 3*u))*DD;
    const float* st  = sem + DD;
    const float* em  = st + DD;
    const float* sc  = sem_cls + ((size_t)(b*UU + u))*DD;
    unsigned short* de = deltaB + ((size_t)(b*UU + u))*DD;
    float* oe = o_emo + ((size_t)(b*UU + u))*DD;
    int t = threadIdx.x;
    for (int d = t; d < DD; d += 256) {
        float dl = sem[d] - sc[d];
        de[d] = f2b(dl); oe[d] = em[d];
        if (u == UU-1) { o_last_stra[b*DD + d] = st[d]; o_last_delta[b*DD + d] = dl; }
    }
    if (t < 224) {
        int o = t >> 4, c = t & 15;
        float s = 0.0f;
        if (o < 8) {
            for (int d = c*64; d < c*64 + 64; ++d) s += st[d]*strW[d*8 + o];
        } else {
            int j = o - 8;
            for (int d = c*64; d < c*64 + 64; ++d) s += em[d]*emoW[d*6 + j];
        }
        part[o][c] = s;
    }
    __syncthreads();
    if (t < 14) {
        float s = 0.0f;
        #pragma unroll
        for (int c2 = 0; c2 < 16; ++c2) s += part[t][c2];
        if (t < 8) o_str[(b*UU + u)*8 + t] = s + strB[t];
        else       o_emo_log[(b*UU + u)*6 + (t-8)] = s + emoB[t-8];
    }
}

// ---------------------------------------------------------------------------
extern "C" void kernel_launch(void* const* d_in, const int* in_sizes, int n_in,
                              void* d_out, int out_size, void* d_ws, size_t ws_size,
                              hipStream_t stream)
{
    const float* hidden  = (const float*)d_in[0];
    const float* emo_csk = (const float*)d_in[1];
    const float* Wq  = (const float*)d_in[2];
    const float* bq  = (const float*)d_in[3];
    const float* Wk  = (const float*)d_in[4];
    const float* bk  = (const float*)d_in[5];
    const float* Wv  = (const float*)d_in[6];
    const float* bv  = (const float*)d_in[7];
    const float* rel = (const float*)d_in[8];
    const float* fusW = (const float*)d_in[9];
    const float* fusB = (const float*)d_in[10];
    const float* bng = (const float*)d_in[11];
    const float* bnb = (const float*)d_in[12];
    const float* bnm = (const float*)d_in[13];
    const float* bnv = (const float*)d_in[14];
    const float* cskW = (const float*)d_in[15];
    const float* cskB = (const float*)d_in[16];
    const float* emoW = (const float*)d_in[17];
    const float* emoB = (const float*)d_in[18];
    const float* strW = (const float*)d_in[19];
    const float* strB = (const float*)d_in[20];
    const float* bowW = (const float*)d_in[21];
    const int* clsIdx = (const int*)d_in[22];
    const int* tGraph = (const int*)d_in[23];
    const int* iGraph = (const int*)d_in[24];
    const int* tEdge  = (const int*)d_in[25];
    const int* iEdge  = (const int*)d_in[26];

    float* out = (float*)d_out;
    float* o_last_stra  = out;             // B*D          = 8192
    float* o_emo_trans  = out + 8192;      // B*U*D        = 196608
    float* o_last_delta = out + 204800;    // B*D          = 8192
    float* o_sem_cls    = out + 212992;    // B*U*D        = 196608
    float* o_str_log    = out + 409600;    // B*U*8        = 1536
    float* o_emo_log    = out + 411136;    // B*U*6        = 1152
    float* o_bow        = out + 412288;    // B*U*VOCAB

    float* ws = (float*)d_ws;
    const int SZ_BTD = BB*TT*DD;   // 589824
    const int SZ_BUD = BB*UU*DD;   // 196608
    float* trans_in  = ws;
    float* Qb        = trans_in + SZ_BTD;
    float* Kb        = Qb + SZ_BTD;
    float* Vb        = Kb + SZ_BTD;
    float* trans_out = Vb + SZ_BTD;
    float* inter_out = trans_out + SZ_BTD;
    float* outsB     = inter_out + SZ_BTD;
    float* csk_norm  = outsB + SZ_BTD;
    unsigned short* deltaB = (unsigned short*)(csk_norm + SZ_BUD);

    // 1. gather cls + batchnorm (merged, grid-split)
    k_gather_bn<<<dim3(BB*UU + (BB*UU*CSKN+255)/256), dim3(256), 0, stream>>>(
            hidden, clsIdx, o_sem_cls, trans_in, emo_csk, bng, bnb, bnm, bnv, csk_norm);
    // 2. csk_proj GEMM fused with scatter-add into trans_in[:,2::3]
    mm64<4><<<dim3(16, 3), dim3(256), 0, stream>>>(csk_norm, nullptr, CSKN, cskW, cskB,
            nullptr, nullptr, trans_in, DD, CSKN);

    auto attention = [&](const float* x, const int* graph, const int* edge, float* ctx_out) {
        mm_qkv<<<dim3(24, (BB*TT)/64), dim3(256), 0, stream>>>(x, Wq, Wk, Wv, bq, bk, bv, Qb, Kb, Vb);
        k_attn<<<dim3(BB*HH*2), dim3(512), 0, stream>>>(Qb, Kb, Vb, edge, rel, graph, ctx_out);
    };
    attention(trans_in, tGraph, tEdge, trans_out);
    attention(trans_out, iGraph, iEdge, inter_out);

    // fusion gate + blend fused: outsB = g*trans + (1-g)*inter
    mm64<3><<<dim3(16, (BB*TT)/64), dim3(256), 0, stream>>>(trans_out, inter_out, DD, fusW, fusB,
            trans_out, inter_out, outsB, DD, 2*DD);

    // merged epilogue (writes deltaB bf16 + small logits)
    k_finlog<<<dim3(BB*UU), dim3(256), 0, stream>>>(outsB, o_sem_cls, strW, strB, emoW, emoB,
            o_last_stra, o_emo_trans, o_last_delta, o_str_log, o_emo_log, deltaB);

    // bow_logits = delta @ bow_W (R6 best-measured variant)
    mm_bow<<<dim3((NVOCAB+63)/64), dim3(256), 0, stream>>>(deltaB, bowW, o_bow);
}

// Round 12
// 311.826 us; speedup vs baseline: 1.2543x; 1.0422x over previous
//
#include <hip/hip_runtime.h>
#include <math.h>

// Problem constants
#define BB 8
#define LL 512
#define UU 24
#define DD 1024
#define HH 16
#define DH 64
#define TT 72
#define CSKN 1024
#define NVOCAB 54945

typedef __attribute__((ext_vector_type(8))) short bf16x8;
typedef __attribute__((ext_vector_type(4))) float f32x4;

__device__ inline unsigned short f2b(float x) {
    unsigned u = __float_as_uint(x);
    unsigned r = u + 0x7FFFu + ((u >> 16) & 1u);
    return (unsigned short)(r >> 16);
}
__device__ inline unsigned pack2(float lo, float hi) {
    return (unsigned)f2b(lo) | ((unsigned)f2b(hi) << 16);
}
__device__ inline void dec8(uint2 c, float* cr) {
    cr[0] = (float)( c.x        & 0xff); cr[1] = (float)((c.x >>  8) & 0xff);
    cr[2] = (float)((c.x >> 16) & 0xff); cr[3] = (float)((c.x >> 24) & 0xff);
    cr[4] = (float)( c.y        & 0xff); cr[5] = (float)((c.y >>  8) & 0xff);
    cr[6] = (float)((c.y >> 16) & 0xff); cr[7] = (float)((c.y >> 24) & 0xff);
}

// ---------------------------------------------------------------------------
// Merged: gather cls (blocks 0..191) + batchnorm (blocks 192..959)
__global__ __launch_bounds__(256) void k_gather_bn(const float* __restrict__ hidden,
        const int* __restrict__ idx, float* __restrict__ sem_cls, float* __restrict__ trans_in,
        const float* __restrict__ x, const float* __restrict__ g,
        const float* __restrict__ be, const float* __restrict__ mu,
        const float* __restrict__ var, float* __restrict__ y)
{
    int bid = blockIdx.x;
    if (bid < BB*UU) {
        int b = bid / UU, u = bid % UU;
        int row = idx[b*UU + u];
        const float* src = hidden + ((size_t)(b*LL + row))*DD;
        float* d0 = trans_in + ((size_t)(b*TT + 3*u))*DD;
        float* sc = sem_cls + ((size_t)(b*UU + u))*DD;
        for (int d = threadIdx.x; d < DD; d += 256) {
            float v = src[d];
            sc[d] = v;
            d0[d] = v; d0[DD + d] = v; d0[2*DD + d] = v;
        }
    } else {
        int i = (bid - BB*UU)*256 + threadIdx.x;
        int n = BB*UU*CSKN;
        if (i < n) {
            int c = i % CSKN;
            y[i] = (x[i] - mu[c]) * (1.0f/sqrtf(var[c] + 1e-5f)) * g[c] + be[c];
        }
    }
}

// ---------------------------------------------------------------------------
// Double-buffered MFMA bf16 GEMM, 64x64 tile, 256 thr, 4 waves (2x2).
// EPI: 3 = gate-blend C=g*ep1+(1-g)*ep2, g=sigmoid(A@B+bias)
//      4 = csk: trans_in[b*72+3u+2][cc] += (A@B+bias), skip u==U-1 (C=trans_in)
template<int EPI>
__global__ __launch_bounds__(256) void mm64(
        const float* __restrict__ A1, const float* __restrict__ A2, int K1,
        const float* __restrict__ Bm, const float* __restrict__ bias,
        const float* __restrict__ ep1, const float* __restrict__ ep2,
        float* __restrict__ C, int N, int K)
{
    __shared__ __align__(16) unsigned short As[2][64][40];
    __shared__ __align__(16) unsigned short Bs[2][64][40];
    int tid = threadIdx.x;
    int wave = tid >> 6, lane = tid & 63;
    int l16 = lane & 15, g = lane >> 4;
    int wm = wave & 1, wn = wave >> 1;
    int row0 = blockIdx.y * 64, col0 = blockIdx.x * 64;

    int ar = tid >> 2, akq = (tid & 3) * 8;
    int bj0 = (tid & 31) * 2, bk0 = (tid >> 5) * 2;
    float4 a0, a1;
    float2 q00, q01, q10, q11;

    auto loadT = [&](int k0) {
        int kk = k0 + akq;
        const float* src = (kk < K1) ? A1 + (size_t)(row0+ar)*K1 + kk
                                     : A2 + (size_t)(row0+ar)*(K-K1) + (kk-K1);
        a0 = *(const float4*)src; a1 = *(const float4*)(src+4);
        const float* bs0 = Bm + (size_t)(k0 + bk0)*N + col0 + bj0;
        q00 = *(const float2*)bs0;       q01 = *(const float2*)(bs0 + N);
        const float* bs1 = bs0 + (size_t)16*N;
        q10 = *(const float2*)bs1;       q11 = *(const float2*)(bs1 + N);
    };
    auto storeT = [&](int buf) {
        unsigned* da = (unsigned*)&As[buf][ar][akq];
        da[0] = pack2(a0.x, a0.y); da[1] = pack2(a0.z, a0.w);
        da[2] = pack2(a1.x, a1.y); da[3] = pack2(a1.z, a1.w);
        *(unsigned*)&Bs[buf][bj0  ][bk0]    = pack2(q00.x, q01.x);
        *(unsigned*)&Bs[buf][bj0+1][bk0]    = pack2(q00.y, q01.y);
        *(unsigned*)&Bs[buf][bj0  ][bk0+16] = pack2(q10.x, q11.x);
        *(unsigned*)&Bs[buf][bj0+1][bk0+16] = pack2(q10.y, q11.y);
    };

    f32x4 acc[2][2] = {};
    loadT(0); storeT(0);
    __syncthreads();
    int nt = K / 32;
    for (int t = 0; t < nt; ++t) {
        int cur = t & 1;
        if (t + 1 < nt) loadT((t+1)*32);
        bf16x8 af[2], bfr[2];
        #pragma unroll
        for (int mf = 0; mf < 2; ++mf) af[mf] = *(const bf16x8*)&As[cur][wm*32 + mf*16 + l16][g*8];
        #pragma unroll
        for (int nf = 0; nf < 2; ++nf) bfr[nf] = *(const bf16x8*)&Bs[cur][wn*32 + nf*16 + l16][g*8];
        #pragma unroll
        for (int mf = 0; mf < 2; ++mf)
            #pragma unroll
            for (int nf = 0; nf < 2; ++nf)
                acc[mf][nf] = __builtin_amdgcn_mfma_f32_16x16x32_bf16(af[mf], bfr[nf], acc[mf][nf], 0, 0, 0);
        if (t + 1 < nt) storeT(cur ^ 1);
        __syncthreads();
    }
    #pragma unroll
    for (int mf = 0; mf < 2; ++mf)
        #pragma unroll
        for (int nf = 0; nf < 2; ++nf) {
            int cc = col0 + wn*32 + nf*16 + l16;
            float bv = bias[cc];
            #pragma unroll
            for (int r = 0; r < 4; ++r) {
                int rr = row0 + wm*32 + mf*16 + g*4 + r;
                float v = acc[mf][nf][r] + bv;
                if (EPI == 3) {
                    float gg = 1.0f/(1.0f + __expf(-v));
                    float tv = ep1[(size_t)rr*N + cc];
                    float iv = ep2[(size_t)rr*N + cc];
                    C[(size_t)rr*N + cc] = gg*tv + (1.0f - gg)*iv;
                } else { // EPI == 4
                    int bq = rr / UU, uq = rr % UU;
                    if (uq < UU-1) {
                        float* dst = &C[((size_t)(bq*TT + 3*uq + 2))*DD + cc];
                        *dst += v;
                    }
                }
            }
        }
}

// ---------------------------------------------------------------------------
// Fused Q/K/V projection, BM=64 BN=128, dbuf. Grid (24, 9); blockIdx.x>>3 selects.
__global__ __launch_bounds__(256) void mm_qkv(
        const float* __restrict__ x,
        const float* __restrict__ W0, const float* __restrict__ W1, const float* __restrict__ W2,
        const float* __restrict__ v0, const float* __restrict__ v1, const float* __restrict__ v2,
        float* __restrict__ C0, float* __restrict__ C1, float* __restrict__ C2)
{
    __shared__ __align__(16) unsigned short As[2][64][40];
    __shared__ __align__(16) unsigned short Bs[2][128][40];
    int which = blockIdx.x >> 3;
    int col0 = (blockIdx.x & 7) * 128;
    int row0 = blockIdx.y * 64;
    const float* W  = (which == 0) ? W0 : (which == 1) ? W1 : W2;
    const float* bb = (which == 0) ? v0 : (which == 1) ? v1 : v2;
    float*       C  = (which == 0) ? C0 : (which == 1) ? C1 : C2;
    int tid = threadIdx.x;
    int wave = tid >> 6, lane = tid & 63;
    int l16 = lane & 15, g = lane >> 4;
    int wm = wave & 1, wn = wave >> 1;

    int ar = tid >> 2, akq = (tid & 3) * 8;
    int bj0 = (tid & 63) * 2, ks = tid >> 6;   // 4 k-pair slots per thread
    float4 a0, a1;
    float2 b0[4], b1[4];

    auto loadT = [&](int k0) {
        const float* src = x + (size_t)(row0+ar)*DD + k0 + akq;
        a0 = *(const float4*)src; a1 = *(const float4*)(src+4);
        #pragma unroll
        for (int s = 0; s < 4; ++s) {
            int kb = (ks + 4*s)*2;
            const float* bp = W + (size_t)(k0 + kb)*DD + col0 + bj0;
            b0[s] = *(const float2*)bp;
            b1[s] = *(const float2*)(bp + DD);
        }
    };
    auto storeT = [&](int buf) {
        unsigned* da = (unsigned*)&As[buf][ar][akq];
        da[0] = pack2(a0.x, a0.y); da[1] = pack2(a0.z, a0.w);
        da[2] = pack2(a1.x, a1.y); da[3] = pack2(a1.z, a1.w);
        #pragma unroll
        for (int s = 0; s < 4; ++s) {
            int kb = (ks + 4*s)*2;
            *(unsigned*)&Bs[buf][bj0  ][kb] = pack2(b0[s].x, b1[s].x);
            *(unsigned*)&Bs[buf][bj0+1][kb] = pack2(b0[s].y, b1[s].y);
        }
    };

    f32x4 acc[2][4] = {};
    loadT(0); storeT(0);
    __syncthreads();
    for (int t = 0; t < 32; ++t) {
        int cur = t & 1;
        if (t < 31) loadT((t+1)*32);
        bf16x8 af[2], bfr[4];
        #pragma unroll
        for (int mf = 0; mf < 2; ++mf) af[mf] = *(const bf16x8*)&As[cur][wm*32 + mf*16 + l16][g*8];
        #pragma unroll
        for (int nf = 0; nf < 4; ++nf) bfr[nf] = *(const bf16x8*)&Bs[cur][wn*64 + nf*16 + l16][g*8];
        #pragma unroll
        for (int mf = 0; mf < 2; ++mf)
            #pragma unroll
            for (int nf = 0; nf < 4; ++nf)
                acc[mf][nf] = __builtin_amdgcn_mfma_f32_16x16x32_bf16(af[mf], bfr[nf], acc[mf][nf], 0, 0, 0);
        if (t < 31) storeT(cur ^ 1);
        __syncthreads();
    }
    #pragma unroll
    for (int mf = 0; mf < 2; ++mf)
        #pragma unroll
        for (int nf = 0; nf < 4; ++nf) {
            int cc = col0 + wn*64 + nf*16 + l16;
            float bv = bb[cc];
            #pragma unroll
            for (int r = 0; r < 4; ++r) {
                int rr = row0 + wm*32 + mf*16 + g*4 + r;
                C[(size_t)rr*DD + cc] = acc[mf][nf][r] + bv;
            }
        }
}

// ---------------------------------------------------------------------------
// bow GEMM v7: deltaB(bf16)[192,1024] @ bowW[1024,54945] -> o_bow.
// 256 thr / 4 waves; wave owns 16 cols; B direct from global, 4-deep prefetch.
// A staged in ONE 52KB LDS buffer per 128-k chunk: barriers only every 4
// k-steps (14 drains vs 32) so the B prefetch queue survives between them.
// Next A-chunk's global loads issued at super-step start (T14 split).
__global__ __launch_bounds__(256, 1) void mm_bow(
        const unsigned short* __restrict__ Ab, const float* __restrict__ Bm,
        float* __restrict__ C)
{
    __shared__ __align__(16) unsigned short A_lds[192][136];   // 52.2 KB
    const int N = NVOCAB;
    int tid = threadIdx.x;
    int lane = tid & 63, wave = tid >> 6;
    int l16 = lane & 15, g = lane >> 4;
    int col = blockIdx.x * 64 + wave * 16 + l16;
    int colc = (col < N) ? col : (N - 1);
    const float* bbase = Bm + (size_t)(g * 8) * N + colc;

    // A chunk: 192 rows x 128 k (48KB) -> 12 int4 per thread, coalesced
    int4 areg0, areg1, areg2, areg3, areg4, areg5, areg6, areg7, areg8, areg9, areg10, areg11;
#define AIDX(i) int r##i = ((i)*256 + tid) >> 4, c##i = (((i)*256 + tid) & 15) * 8
    AIDX(0); AIDX(1); AIDX(2); AIDX(3); AIDX(4); AIDX(5);
    AIDX(6); AIDX(7); AIDX(8); AIDX(9); AIDX(10); AIDX(11);
#undef AIDX
#define LOADA(s) {                                                             \
        const unsigned short* ab = Ab + (s)*128;                               \
        areg0  = *(const int4*)(ab + (size_t)r0*DD  + c0);                     \
        areg1  = *(const int4*)(ab + (size_t)r1*DD  + c1);                     \
        areg2  = *(const int4*)(ab + (size_t)r2*DD  + c2);                     \
        areg3  = *(const int4*)(ab + (size_t)r3*DD  + c3);                     \
        areg4  = *(const int4*)(ab + (size_t)r4*DD  + c4);                     \
        areg5  = *(const int4*)(ab + (size_t)r5*DD  + c5);                     \
        areg6  = *(const int4*)(ab + (size_t)r6*DD  + c6);                     \
        areg7  = *(const int4*)(ab + (size_t)r7*DD  + c7);                     \
        areg8  = *(const int4*)(ab + (size_t)r8*DD  + c8);                     \
        areg9  = *(const int4*)(ab + (size_t)r9*DD  + c9);                     \
        areg10 = *(const int4*)(ab + (size_t)r10*DD + c10);                    \
        areg11 = *(const int4*)(ab + (size_t)r11*DD + c11);                    \
    }
#define WRITEA() {                                                             \
        *(int4*)&A_lds[r0][c0]   = areg0;  *(int4*)&A_lds[r1][c1]   = areg1;   \
        *(int4*)&A_lds[r2][c2]   = areg2;  *(int4*)&A_lds[r3][c3]   = areg3;   \
        *(int4*)&A_lds[r4][c4]   = areg4;  *(int4*)&A_lds[r5][c5]   = areg5;   \
        *(int4*)&A_lds[r6][c6]   = areg6;  *(int4*)&A_lds[r7][c7]   = areg7;   \
        *(int4*)&A_lds[r8][c8]   = areg8;  *(int4*)&A_lds[r9][c9]   = areg9;   \
        *(int4*)&A_lds[r10][c10] = areg10; *(int4*)&A_lds[r11][c11] = areg11;  \
    }

    f32x4 acc[12] = {};
    float bs[4][8];

#define LOADB(dst, t_) { const float* bp = bbase + (size_t)(t_) * 32 * N;      \
        _Pragma("unroll") for (int j = 0; j < 8; ++j) dst[j] = bp[(size_t)j * N]; }
#define PACKB(fr, sv) { _Pragma("unroll") for (int j = 0; j < 8; ++j)          \
        ((unsigned short*)&fr)[j] = f2b(sv[j]); }

    LOADA(0); WRITEA();
    #pragma unroll
    for (int p = 0; p < 4; ++p) LOADB(bs[p], p);
    __syncthreads();

    for (int s = 0; s < 8; ++s) {
        if (s < 7) LOADA(s + 1);           // early issue; lands before WRITEA
        #pragma unroll
        for (int p = 0; p < 4; ++p) {
            int P = s*4 + p;
            bf16x8 fr;
            PACKB(fr, bs[p]);
            if (P + 4 < 32) LOADB(bs[p], P + 4);
            #pragma unroll
            for (int mf = 0; mf < 12; ++mf) {
                bf16x8 af = *(const bf16x8*)&A_lds[mf*16 + l16][p*32 + g*8];
                acc[mf] = __builtin_amdgcn_mfma_f32_16x16x32_bf16(af, fr, acc[mf], 0, 0, 0);
            }
        }
        if (s < 7) {
            __syncthreads();               // all waves done with chunk s
            WRITEA();                      // chunk s+1 -> LDS
            __syncthreads();               // visible to all
        }
    }
#undef LOADA
#undef WRITEA
#undef LOADB
#undef PACKB
    if (col < N) {
        #pragma unroll
        for (int mf = 0; mf < 12; ++mf)
            #pragma unroll
            for (int r = 0; r < 4; ++r)
                C[(size_t)(mf * 16 + g * 4 + r) * N + col] = acc[mf][r];
    }
}

// ---------------------------------------------------------------------------
// Fully fused attention per (b,h,half): edge prefix (cnt) computed IN-BLOCK,
// prep (A=Q+S_diag, AR) + scores + softmax + PV. Grid B*H*2 = 256 blocks,
// 512 thr (8 waves), 36 rows/block. LDS = 62.8 KB.
__global__ __launch_bounds__(512) void k_attn(const float* __restrict__ Qb,
        const float* __restrict__ Kg, const float* __restrict__ Vg,
        const int* __restrict__ et, const float* __restrict__ rel,
        const int* __restrict__ mask, float* __restrict__ out)
{
    int bid = blockIdx.x;
    int is = bid & 1;
    int h  = (bid >> 1) & (HH-1);
    int b  = bid >> 5;
    int lo = is * (TT/2);
    __shared__ float K_sh[DH][TT+1];          // 18688 B, transposed [d][t]
    __shared__ float V_sh[TT][DH];            // 18432 B, row-major
    __shared__ uint2 cnt_sh[TT/2][TT];        // 20736 B, prefix counts rows [lo,lo+36)
    __shared__ __align__(16) unsigned char un_raw[6400];  // e_sh then rel/a/p
    float (*rel_sh)[DH] = (float(*)[DH])un_raw;           // [8][64]
    float (*a_row)[DH]  = (float(*)[DH])(un_raw + 2048);  // [8][64]
    float (*p_row)[TT]  = (float(*)[TT])(un_raw + 4096);  // [8][72]
    unsigned char* e_sh = un_raw;                          // [5184]
    int tid = threadIdx.x;
    int lane = tid & 63, w = tid >> 6;

    // stage K (transposed) and V
    for (int idx = tid; idx < TT*16; idx += 512) {
        int r = idx >> 4, q4 = (idx & 15) * 4;
        size_t goff = ((size_t)(b*TT + r))*DD + h*DH + q4;
        float4 kv = *(const float4*)&Kg[goff];
        K_sh[q4  ][r] = kv.x; K_sh[q4+1][r] = kv.y;
        K_sh[q4+2][r] = kv.z; K_sh[q4+3][r] = kv.w;
        float4 vv = *(const float4*)&Vg[goff];
        *(float4*)&V_sh[r][q4] = vv;
    }
    // stage edge types (packed u8) into union region
    for (int idx = tid; idx < (TT*TT)/4; idx += 512) {
        int4 v = ((const int4*)(et + (size_t)b*TT*TT))[idx];
        unsigned pk = (unsigned)v.x | ((unsigned)v.y << 8) | ((unsigned)v.z << 16) | ((unsigned)v.w << 24);
        *(unsigned*)&e_sh[idx*4] = pk;
    }
    __syncthreads();
    // in-block prefix counts along i for this half's rows
    if (tid < TT) {
        unsigned lo32 = 0, hi32 = 0;
        int iend = lo + TT/2;
        for (int i = 0; i < iend; ++i) {
            int r = e_sh[i*TT + tid];
            if (r < 4) lo32 += 1u << (8*r); else hi32 += 1u << (8*(r-4));
            if (i >= lo) cnt_sh[i - lo][tid] = make_uint2(lo32, hi32);
        }
    }
    __syncthreads();
    // load rel into union region (e_sh no longer needed)
    if (tid < 128) {
        int r = tid >> 4, q4 = (tid & 15) * 4;
        *(float4*)&rel_sh[r][q4] = *(const float4*)&rel[r*DD + h*DH + q4];
    }
    __syncthreads();

    for (int ii = w; ii < TT/2; ii += 8) {
        int i = lo + ii;
        size_t rowoff = (size_t)(b*TT + i);
        // --- prep: a = q + sum_r cr[r]*rel_r ; AR[r] = <a, rel_r>
        float q = Qb[rowoff*DD + h*DH + lane];
        float crd[8]; dec8(cnt_sh[ii][i], crd);
        float a = q;
        #pragma unroll
        for (int r = 0; r < 8; ++r) a += crd[r]*rel_sh[r][lane];
        a_row[w][lane] = a;
        float arr[8];
        #pragma unroll
        for (int r = 0; r < 8; ++r) {
            float pr = a * rel_sh[r][lane];
            #pragma unroll
            for (int off = 32; off; off >>= 1) pr += __shfl_xor(pr, off);
            arr[r] = pr;
        }
        // --- scores: pass1 key t=lane, pass2 key t=64+lane (lane<8)
        float s1;
        {
            int t = lane;
            float s = 0.0f;
            #pragma unroll
            for (int d0 = 0; d0 < DH; d0 += 4) {
                float4 av = *(const float4*)&a_row[w][d0];
                s += av.x*K_sh[d0][t] + av.y*K_sh[d0+1][t]
                   + av.z*K_sh[d0+2][t] + av.w*K_sh[d0+3][t];
            }
            float cr2[8]; dec8(cnt_sh[ii][t], cr2);
            float s2v = cr2[0]*arr[0] + cr2[1]*arr[1] + cr2[2]*arr[2] + cr2[3]*arr[3]
                      + cr2[4]*arr[4] + cr2[5]*arr[5] + cr2[6]*arr[6] + cr2[7]*arr[7];
            int m = mask[rowoff*TT + t];
            s1 = (m == 0) ? -1e9f : (s + s2v)*0.125f;
        }
        float s2 = -1e30f;
        if (lane < TT - DH) {
            int t = DH + lane;
            float s = 0.0f;
            #pragma unroll
            for (int d0 = 0; d0 < DH; d0 += 4) {
                float4 av = *(const float4*)&a_row[w][d0];
                s += av.x*K_sh[d0][t] + av.y*K_sh[d0+1][t]
                   + av.z*K_sh[d0+2][t] + av.w*K_sh[d0+3][t];
            }
            float cr2[8]; dec8(cnt_sh[ii][t], cr2);
            float s2v = cr2[0]*arr[0] + cr2[1]*arr[1] + cr2[2]*arr[2] + cr2[3]*arr[3]
                      + cr2[4]*arr[4] + cr2[5]*arr[5] + cr2[6]*arr[6] + cr2[7]*arr[7];
            int m = mask[rowoff*TT + t];
            s2 = (m == 0) ? -1e9f : (s + s2v)*0.125f;
        }
        // --- softmax over 72
        float mx = fmaxf(s1, s2);
        #pragma unroll
        for (int off = 32; off; off >>= 1) mx = fmaxf(mx, __shfl_xor(mx, off));
        float e1 = __expf(s1 - mx);
        float e2 = (lane < TT - DH) ? __expf(s2 - mx) : 0.0f;
        float sm = e1 + e2;
        #pragma unroll
        for (int off = 32; off; off >>= 1) sm += __shfl_xor(sm, off);
        float inv = 1.0f / sm;
        p_row[w][lane] = e1 * inv;
        if (lane < TT - DH) p_row[w][DH + lane] = e2 * inv;
        // --- PV: lane owns d = lane
        float o = 0.0f;
        #pragma unroll 8
        for (int t = 0; t < TT; ++t) o += p_row[w][t] * V_sh[t][lane];
        out[rowoff*DD + h*DH + lane] = o;
    }
}

// ---------------------------------------------------------------------------
// Merged epilogue: output splits + delta(bf16) + strategy/emotion logits
__global__ __launch_bounds__(256) void k_finlog(const float* __restrict__ outs,
        const float* __restrict__ sem_cls,
        const float* __restrict__ strW, const float* __restrict__ strB,
        const float* __restrict__ emoW, const float* __restrict__ emoB,
        float* __restrict__ o_last_stra, float* __restrict__ o_emo,
        float* __restrict__ o_last_delta, float* __restrict__ o_str,
        float* __restrict__ o_emo_log, unsigned short* __restrict__ deltaB)
{
    __shared__ float part[14][16];
    int bid = blockIdx.x; int b = bid / UU, u = bid % UU;
    const float* sem = outs + ((size_t)(b*TT + 3*u))*DD;
    const float* st  = sem + DD;
    const float* em  = st + DD;
    const float* sc  = sem_cls + ((size_t)(b*UU + u))*DD;
    unsigned short* de = deltaB + ((size_t)(b*UU + u))*DD;
    float* oe = o_emo + ((size_t)(b*UU + u))*DD;
    int t = threadIdx.x;
    for (int d = t; d < DD; d += 256) {
        float dl = sem[d] - sc[d];
        de[d] = f2b(dl); oe[d] = em[d];
        if (u == UU-1) { o_last_stra[b*DD + d] = st[d]; o_last_delta[b*DD + d] = dl; }
    }
    if (t < 224) {
        int o = t >> 4, c = t & 15;
        float s = 0.0f;
        if (o < 8) {
            for (int d = c*64; d < c*64 + 64; ++d) s += st[d]*strW[d*8 + o];
        } else {
            int j = o - 8;
            for (int d = c*64; d < c*64 + 64; ++d) s += em[d]*emoW[d*6 + j];
        }
        part[o][c] = s;
    }
    __syncthreads();
    if (t < 14) {
        float s = 0.0f;
        #pragma unroll
        for (int c2 = 0; c2 < 16; ++c2) s += part[t][c2];
        if (t < 8) o_str[(b*UU + u)*8 + t] = s + strB[t];
        else       o_emo_log[(b*UU + u)*6 + (t-8)] = s + emoB[t-8];
    }
}

// ---------------------------------------------------------------------------
extern "C" void kernel_launch(void* const* d_in, const int* in_sizes, int n_in,
                              void* d_out, int out_size, void* d_ws, size_t ws_size,
                              hipStream_t stream)
{
    const float* hidden  = (const float*)d_in[0];
    const float* emo_csk = (const float*)d_in[1];
    const float* Wq  = (const float*)d_in[2];
    const float* bq  = (const float*)d_in[3];
    const float* Wk  = (const float*)d_in[4];
    const float* bk  = (const float*)d_in[5];
    const float* Wv  = (const float*)d_in[6];
    const float* bv  = (const float*)d_in[7];
    const float* rel = (const float*)d_in[8];
    const float* fusW = (const float*)d_in[9];
    const float* fusB = (const float*)d_in[10];
    const float* bng = (const float*)d_in[11];
    const float* bnb = (const float*)d_in[12];
    const float* bnm = (const float*)d_in[13];
    const float* bnv = (const float*)d_in[14];
    const float* cskW = (const float*)d_in[15];
    const float* cskB = (const float*)d_in[16];
    const float* emoW = (const float*)d_in[17];
    const float* emoB = (const float*)d_in[18];
    const float* strW = (const float*)d_in[19];
    const float* strB = (const float*)d_in[20];
    const float* bowW = (const float*)d_in[21];
    const int* clsIdx = (const int*)d_in[22];
    const int* tGraph = (const int*)d_in[23];
    const int* iGraph = (const int*)d_in[24];
    const int* tEdge  = (const int*)d_in[25];
    const int* iEdge  = (const int*)d_in[26];

    float* out = (float*)d_out;
    float* o_last_stra  = out;             // B*D          = 8192
    float* o_emo_trans  = out + 8192;      // B*U*D        = 196608
    float* o_last_delta = out + 204800;    // B*D          = 8192
    float* o_sem_cls    = out + 212992;    // B*U*D        = 196608
    float* o_str_log    = out + 409600;    // B*U*8        = 1536
    float* o_emo_log    = out + 411136;    // B*U*6        = 1152
    float* o_bow        = out + 412288;    // B*U*VOCAB

    float* ws = (float*)d_ws;
    const int SZ_BTD = BB*TT*DD;   // 589824
    const int SZ_BUD = BB*UU*DD;   // 196608
    float* trans_in  = ws;
    float* Qb        = trans_in + SZ_BTD;
    float* Kb        = Qb + SZ_BTD;
    float* Vb        = Kb + SZ_BTD;
    float* trans_out = Vb + SZ_BTD;
    float* inter_out = trans_out + SZ_BTD;
    float* outsB     = inter_out + SZ_BTD;
    float* csk_norm  = outsB + SZ_BTD;
    unsigned short* deltaB = (unsigned short*)(csk_norm + SZ_BUD);

    // 1. gather cls + batchnorm (merged, grid-split)
    k_gather_bn<<<dim3(BB*UU + (BB*UU*CSKN+255)/256), dim3(256), 0, stream>>>(
            hidden, clsIdx, o_sem_cls, trans_in, emo_csk, bng, bnb, bnm, bnv, csk_norm);
    // 2. csk_proj GEMM fused with scatter-add into trans_in[:,2::3]
    mm64<4><<<dim3(16, 3), dim3(256), 0, stream>>>(csk_norm, nullptr, CSKN, cskW, cskB,
            nullptr, nullptr, trans_in, DD, CSKN);

    auto attention = [&](const float* x, const int* graph, const int* edge, float* ctx_out) {
        mm_qkv<<<dim3(24, (BB*TT)/64), dim3(256), 0, stream>>>(x, Wq, Wk, Wv, bq, bk, bv, Qb, Kb, Vb);
        k_attn<<<dim3(BB*HH*2), dim3(512), 0, stream>>>(Qb, Kb, Vb, edge, rel, graph, ctx_out);
    };
    attention(trans_in, tGraph, tEdge, trans_out);
    attention(trans_out, iGraph, iEdge, inter_out);

    // fusion gate + blend fused: outsB = g*trans + (1-g)*inter
    mm64<3><<<dim3(16, (BB*TT)/64), dim3(256), 0, stream>>>(trans_out, inter_out, DD, fusW, fusB,
            trans_out, inter_out, outsB, DD, 2*DD);

    // merged epilogue (writes deltaB bf16 + small logits)
    k_finlog<<<dim3(BB*UU), dim3(256), 0, stream>>>(outsB, o_sem_cls, strW, strB, emoW, emoB,
            o_last_stra, o_emo_trans, o_last_delta, o_str_log, o_emo_log, deltaB);

    // bow_logits = delta @ bow_W (barrier-amortized: 14 drains vs 32)
    mm_bow<<<dim3((NVOCAB+63)/64), dim3(256), 0, stream>>>(deltaB, bowW, o_bow);
}

// Round 13
// 275.342 us; speedup vs baseline: 1.4206x; 1.1325x over previous
//
#include <hip/hip_runtime.h>
#include <math.h>

// Problem constants
#define BB 8
#define LL 512
#define UU 24
#define DD 1024
#define HH 16
#define DH 64
#define TT 72
#define CSKN 1024
#define NVOCAB 54945

typedef __attribute__((ext_vector_type(8))) short bf16x8;
typedef __attribute__((ext_vector_type(4))) float f32x4;

__device__ inline unsigned short f2b(float x) {
    unsigned u = __float_as_uint(x);
    unsigned r = u + 0x7FFFu + ((u >> 16) & 1u);
    return (unsigned short)(r >> 16);
}
__device__ inline unsigned pack2(float lo, float hi) {
    return (unsigned)f2b(lo) | ((unsigned)f2b(hi) << 16);
}
__device__ inline void dec8(uint2 c, float* cr) {
    cr[0] = (float)( c.x        & 0xff); cr[1] = (float)((c.x >>  8) & 0xff);
    cr[2] = (float)((c.x >> 16) & 0xff); cr[3] = (float)((c.x >> 24) & 0xff);
    cr[4] = (float)( c.y        & 0xff); cr[5] = (float)((c.y >>  8) & 0xff);
    cr[6] = (float)((c.y >> 16) & 0xff); cr[7] = (float)((c.y >> 24) & 0xff);
}

// ---------------------------------------------------------------------------
// Merged: gather cls (blocks 0..191) + batchnorm (blocks 192..959)
__global__ __launch_bounds__(256) void k_gather_bn(const float* __restrict__ hidden,
        const int* __restrict__ idx, float* __restrict__ sem_cls, float* __restrict__ trans_in,
        const float* __restrict__ x, const float* __restrict__ g,
        const float* __restrict__ be, const float* __restrict__ mu,
        const float* __restrict__ var, float* __restrict__ y)
{
    int bid = blockIdx.x;
    if (bid < BB*UU) {
        int b = bid / UU, u = bid % UU;
        int row = idx[b*UU + u];
        const float* src = hidden + ((size_t)(b*LL + row))*DD;
        float* d0 = trans_in + ((size_t)(b*TT + 3*u))*DD;
        float* sc = sem_cls + ((size_t)(b*UU + u))*DD;
        for (int d = threadIdx.x; d < DD; d += 256) {
            float v = src[d];
            sc[d] = v;
            d0[d] = v; d0[DD + d] = v; d0[2*DD + d] = v;
        }
    } else {
        int i = (bid - BB*UU)*256 + threadIdx.x;
        int n = BB*UU*CSKN;
        if (i < n) {
            int c = i % CSKN;
            y[i] = (x[i] - mu[c]) * (1.0f/sqrtf(var[c] + 1e-5f)) * g[c] + be[c];
        }
    }
}

// ---------------------------------------------------------------------------
// MFMA bf16 GEMM, 64x64 tile, BK=64 double-buffered (half the barrier drains).
// EPI: 3 = gate-blend C=g*ep1+(1-g)*ep2, g=sigmoid(A@B+bias)
//      4 = csk: trans_in[b*72+3u+2][cc] += (A@B+bias), skip u==U-1 (C=trans_in)
template<int EPI>
__global__ __launch_bounds__(256) void mm64(
        const float* __restrict__ A1, const float* __restrict__ A2, int K1,
        const float* __restrict__ Bm, const float* __restrict__ bias,
        const float* __restrict__ ep1, const float* __restrict__ ep2,
        float* __restrict__ C, int N, int K)
{
    __shared__ __align__(16) unsigned short As[2][64][72];
    __shared__ __align__(16) unsigned short Bs[2][64][72];
    int tid = threadIdx.x;
    int wave = tid >> 6, lane = tid & 63;
    int l16 = lane & 15, g = lane >> 4;
    int wm = wave & 1, wn = wave >> 1;
    int row0 = blockIdx.y * 64, col0 = blockIdx.x * 64;

    int ar = tid >> 2, akq = (tid & 3) * 16;
    int bj0 = (tid & 31) * 2, kp = tid >> 5;   // kp 0..7, 4 pair-slots each
    float4 a0, a1, a2, a3;
    float2 b0[4], b1[4];

    auto loadT = [&](int k0) {
        int kk = k0 + akq;
        const float* src = (kk < K1) ? A1 + (size_t)(row0+ar)*K1 + kk
                                     : A2 + (size_t)(row0+ar)*(K-K1) + (kk-K1);
        a0 = *(const float4*)src;      a1 = *(const float4*)(src+4);
        a2 = *(const float4*)(src+8);  a3 = *(const float4*)(src+12);
        #pragma unroll
        for (int s = 0; s < 4; ++s) {
            int kb = 2*(kp + 8*s);
            const float* bp = Bm + (size_t)(k0 + kb)*N + col0 + bj0;
            b0[s] = *(const float2*)bp;
            b1[s] = *(const float2*)(bp + N);
        }
    };
    auto storeT = [&](int buf) {
        unsigned* da = (unsigned*)&As[buf][ar][akq];
        da[0]=pack2(a0.x,a0.y); da[1]=pack2(a0.z,a0.w);
        da[2]=pack2(a1.x,a1.y); da[3]=pack2(a1.z,a1.w);
        da[4]=pack2(a2.x,a2.y); da[5]=pack2(a2.z,a2.w);
        da[6]=pack2(a3.x,a3.y); da[7]=pack2(a3.z,a3.w);
        #pragma unroll
        for (int s = 0; s < 4; ++s) {
            int kb = 2*(kp + 8*s);
            *(unsigned*)&Bs[buf][bj0  ][kb] = pack2(b0[s].x, b1[s].x);
            *(unsigned*)&Bs[buf][bj0+1][kb] = pack2(b0[s].y, b1[s].y);
        }
    };

    f32x4 acc[2][2] = {};
    loadT(0); storeT(0);
    __syncthreads();
    int nt = K / 64;
    for (int t = 0; t < nt; ++t) {
        int cur = t & 1;
        if (t + 1 < nt) loadT((t+1)*64);
        #pragma unroll
        for (int kk = 0; kk < 2; ++kk) {
            bf16x8 af[2], bfr[2];
            #pragma unroll
            for (int mf = 0; mf < 2; ++mf) af[mf] = *(const bf16x8*)&As[cur][wm*32 + mf*16 + l16][kk*32 + g*8];
            #pragma unroll
            for (int nf = 0; nf < 2; ++nf) bfr[nf] = *(const bf16x8*)&Bs[cur][wn*32 + nf*16 + l16][kk*32 + g*8];
            #pragma unroll
            for (int mf = 0; mf < 2; ++mf)
                #pragma unroll
                for (int nf = 0; nf < 2; ++nf)
                    acc[mf][nf] = __builtin_amdgcn_mfma_f32_16x16x32_bf16(af[mf], bfr[nf], acc[mf][nf], 0, 0, 0);
        }
        if (t + 1 < nt) storeT(cur ^ 1);
        __syncthreads();
    }
    #pragma unroll
    for (int mf = 0; mf < 2; ++mf)
        #pragma unroll
        for (int nf = 0; nf < 2; ++nf) {
            int cc = col0 + wn*32 + nf*16 + l16;
            float bv = bias[cc];
            #pragma unroll
            for (int r = 0; r < 4; ++r) {
                int rr = row0 + wm*32 + mf*16 + g*4 + r;
                float v = acc[mf][nf][r] + bv;
                if (EPI == 3) {
                    float gg = 1.0f/(1.0f + __expf(-v));
                    float tv = ep1[(size_t)rr*N + cc];
                    float iv = ep2[(size_t)rr*N + cc];
                    C[(size_t)rr*N + cc] = gg*tv + (1.0f - gg)*iv;
                } else { // EPI == 4
                    int bq = rr / UU, uq = rr % UU;
                    if (uq < UU-1) {
                        float* dst = &C[((size_t)(bq*TT + 3*uq + 2))*DD + cc];
                        *dst += v;
                    }
                }
            }
        }
}

// ---------------------------------------------------------------------------
// Fused Q/K/V projection, BM=64 BN=128, BK=64 dbuf (16 iters vs 32).
// Grid (24, 9); blockIdx.x>>3 selects Q/K/V.
__global__ __launch_bounds__(256) void mm_qkv(
        const float* __restrict__ x,
        const float* __restrict__ W0, const float* __restrict__ W1, const float* __restrict__ W2,
        const float* __restrict__ v0, const float* __restrict__ v1, const float* __restrict__ v2,
        float* __restrict__ C0, float* __restrict__ C1, float* __restrict__ C2)
{
    __shared__ __align__(16) unsigned short As[2][64][72];
    __shared__ __align__(16) unsigned short Bs[2][128][72];
    int which = blockIdx.x >> 3;
    int col0 = (blockIdx.x & 7) * 128;
    int row0 = blockIdx.y * 64;
    const float* W  = (which == 0) ? W0 : (which == 1) ? W1 : W2;
    const float* bb = (which == 0) ? v0 : (which == 1) ? v1 : v2;
    float*       C  = (which == 0) ? C0 : (which == 1) ? C1 : C2;
    int tid = threadIdx.x;
    int wave = tid >> 6, lane = tid & 63;
    int l16 = lane & 15, g = lane >> 4;
    int wm = wave & 1, wn = wave >> 1;

    int ar = tid >> 2, akq = (tid & 3) * 16;
    int bj0 = (tid & 63) * 2, kp = tid >> 6;   // kp 0..3, 8 pair-slots each
    float4 a0, a1, a2, a3;
    float2 b0[8], b1[8];

    auto loadT = [&](int k0) {
        const float* src = x + (size_t)(row0+ar)*DD + k0 + akq;
        a0 = *(const float4*)src;      a1 = *(const float4*)(src+4);
        a2 = *(const float4*)(src+8);  a3 = *(const float4*)(src+12);
        #pragma unroll
        for (int s = 0; s < 8; ++s) {
            int kb = 2*(kp + 4*s);
            const float* bp = W + (size_t)(k0 + kb)*DD + col0 + bj0;
            b0[s] = *(const float2*)bp;
            b1[s] = *(const float2*)(bp + DD);
        }
    };
    auto storeT = [&](int buf) {
        unsigned* da = (unsigned*)&As[buf][ar][akq];
        da[0]=pack2(a0.x,a0.y); da[1]=pack2(a0.z,a0.w);
        da[2]=pack2(a1.x,a1.y); da[3]=pack2(a1.z,a1.w);
        da[4]=pack2(a2.x,a2.y); da[5]=pack2(a2.z,a2.w);
        da[6]=pack2(a3.x,a3.y); da[7]=pack2(a3.z,a3.w);
        #pragma unroll
        for (int s = 0; s < 8; ++s) {
            int kb = 2*(kp + 4*s);
            *(unsigned*)&Bs[buf][bj0  ][kb] = pack2(b0[s].x, b1[s].x);
            *(unsigned*)&Bs[buf][bj0+1][kb] = pack2(b0[s].y, b1[s].y);
        }
    };

    f32x4 acc[2][4] = {};
    loadT(0); storeT(0);
    __syncthreads();
    for (int t = 0; t < 16; ++t) {
        int cur = t & 1;
        if (t < 15) loadT((t+1)*64);
        #pragma unroll
        for (int kk = 0; kk < 2; ++kk) {
            bf16x8 af[2], bfr[4];
            #pragma unroll
            for (int mf = 0; mf < 2; ++mf) af[mf] = *(const bf16x8*)&As[cur][wm*32 + mf*16 + l16][kk*32 + g*8];
            #pragma unroll
            for (int nf = 0; nf < 4; ++nf) bfr[nf] = *(const bf16x8*)&Bs[cur][wn*64 + nf*16 + l16][kk*32 + g*8];
            #pragma unroll
            for (int mf = 0; mf < 2; ++mf)
                #pragma unroll
                for (int nf = 0; nf < 4; ++nf)
                    acc[mf][nf] = __builtin_amdgcn_mfma_f32_16x16x32_bf16(af[mf], bfr[nf], acc[mf][nf], 0, 0, 0);
        }
        if (t < 15) storeT(cur ^ 1);
        __syncthreads();
    }
    #pragma unroll
    for (int mf = 0; mf < 2; ++mf)
        #pragma unroll
        for (int nf = 0; nf < 4; ++nf) {
            int cc = col0 + wn*64 + nf*16 + l16;
            float bv = bb[cc];
            #pragma unroll
            for (int r = 0; r < 4; ++r) {
                int rr = row0 + wm*32 + mf*16 + g*4 + r;
                C[(size_t)rr*DD + cc] = acc[mf][nf][r] + bv;
            }
        }
}

// ---------------------------------------------------------------------------
// bow GEMM (R11, best measured): deltaB(bf16)[192,1024] @ bowW -> o_bow.
// Barriers every 4 k-steps; B direct from global with 4-deep prefetch.
__global__ __launch_bounds__(256, 1) void mm_bow(
        const unsigned short* __restrict__ Ab, const float* __restrict__ Bm,
        float* __restrict__ C)
{
    __shared__ __align__(16) unsigned short A_lds[192][136];   // 52.2 KB
    const int N = NVOCAB;
    int tid = threadIdx.x;
    int lane = tid & 63, wave = tid >> 6;
    int l16 = lane & 15, g = lane >> 4;
    int col = blockIdx.x * 64 + wave * 16 + l16;
    int colc = (col < N) ? col : (N - 1);
    const float* bbase = Bm + (size_t)(g * 8) * N + colc;

    int4 areg0, areg1, areg2, areg3, areg4, areg5, areg6, areg7, areg8, areg9, areg10, areg11;
#define AIDX(i) int r##i = ((i)*256 + tid) >> 4, c##i = (((i)*256 + tid) & 15) * 8
    AIDX(0); AIDX(1); AIDX(2); AIDX(3); AIDX(4); AIDX(5);
    AIDX(6); AIDX(7); AIDX(8); AIDX(9); AIDX(10); AIDX(11);
#undef AIDX
#define LOADA(s) {                                                             \
        const unsigned short* ab = Ab + (s)*128;                               \
        areg0  = *(const int4*)(ab + (size_t)r0*DD  + c0);                     \
        areg1  = *(const int4*)(ab + (size_t)r1*DD  + c1);                     \
        areg2  = *(const int4*)(ab + (size_t)r2*DD  + c2);                     \
        areg3  = *(const int4*)(ab + (size_t)r3*DD  + c3);                     \
        areg4  = *(const int4*)(ab + (size_t)r4*DD  + c4);                     \
        areg5  = *(const int4*)(ab + (size_t)r5*DD  + c5);                     \
        areg6  = *(const int4*)(ab + (size_t)r6*DD  + c6);                     \
        areg7  = *(const int4*)(ab + (size_t)r7*DD  + c7);                     \
        areg8  = *(const int4*)(ab + (size_t)r8*DD  + c8);                     \
        areg9  = *(const int4*)(ab + (size_t)r9*DD  + c9);                     \
        areg10 = *(const int4*)(ab + (size_t)r10*DD + c10);                    \
        areg11 = *(const int4*)(ab + (size_t)r11*DD + c11);                    \
    }
#define WRITEA() {                                                             \
        *(int4*)&A_lds[r0][c0]   = areg0;  *(int4*)&A_lds[r1][c1]   = areg1;   \
        *(int4*)&A_lds[r2][c2]   = areg2;  *(int4*)&A_lds[r3][c3]   = areg3;   \
        *(int4*)&A_lds[r4][c4]   = areg4;  *(int4*)&A_lds[r5][c5]   = areg5;   \
        *(int4*)&A_lds[r6][c6]   = areg6;  *(int4*)&A_lds[r7][c7]   = areg7;   \
        *(int4*)&A_lds[r8][c8]   = areg8;  *(int4*)&A_lds[r9][c9]   = areg9;   \
        *(int4*)&A_lds[r10][c10] = areg10; *(int4*)&A_lds[r11][c11] = areg11;  \
    }

    f32x4 acc[12] = {};
    float bs[4][8];

#define LOADB(dst, t_) { const float* bp = bbase + (size_t)(t_) * 32 * N;      \
        _Pragma("unroll") for (int j = 0; j < 8; ++j) dst[j] = bp[(size_t)j * N]; }
#define PACKB(fr, sv) { _Pragma("unroll") for (int j = 0; j < 8; ++j)          \
        ((unsigned short*)&fr)[j] = f2b(sv[j]); }

    LOADA(0); WRITEA();
    #pragma unroll
    for (int p = 0; p < 4; ++p) LOADB(bs[p], p);
    __syncthreads();

    for (int s = 0; s < 8; ++s) {
        if (s < 7) LOADA(s + 1);
        #pragma unroll
        for (int p = 0; p < 4; ++p) {
            int P = s*4 + p;
            bf16x8 fr;
            PACKB(fr, bs[p]);
            if (P + 4 < 32) LOADB(bs[p], P + 4);
            #pragma unroll
            for (int mf = 0; mf < 12; ++mf) {
                bf16x8 af = *(const bf16x8*)&A_lds[mf*16 + l16][p*32 + g*8];
                acc[mf] = __builtin_amdgcn_mfma_f32_16x16x32_bf16(af, fr, acc[mf], 0, 0, 0);
            }
        }
        if (s < 7) {
            __syncthreads();
            WRITEA();
            __syncthreads();
        }
    }
#undef LOADA
#undef WRITEA
#undef LOADB
#undef PACKB
    if (col < N) {
        #pragma unroll
        for (int mf = 0; mf < 12; ++mf)
            #pragma unroll
            for (int r = 0; r < 4; ++r)
                C[(size_t)(mf * 16 + g * 4 + r) * N + col] = acc[mf][r];
    }
}

// ---------------------------------------------------------------------------
// Fully fused attention per (b,h,half): edge prefix in-block, prep + scores +
// softmax + PV. 256 blocks, 512 thr. Q rows batch-prefetched (5 loads upfront).
__global__ __launch_bounds__(512) void k_attn(const float* __restrict__ Qb,
        const float* __restrict__ Kg, const float* __restrict__ Vg,
        const int* __restrict__ et, const float* __restrict__ rel,
        const int* __restrict__ mask, float* __restrict__ out)
{
    int bid = blockIdx.x;
    int is = bid & 1;
    int h  = (bid >> 1) & (HH-1);
    int b  = bid >> 5;
    int lo = is * (TT/2);
    __shared__ float K_sh[DH][TT+1];
    __shared__ float V_sh[TT][DH];
    __shared__ uint2 cnt_sh[TT/2][TT];
    __shared__ __align__(16) unsigned char un_raw[6400];
    float (*rel_sh)[DH] = (float(*)[DH])un_raw;
    float (*a_row)[DH]  = (float(*)[DH])(un_raw + 2048);
    float (*p_row)[TT]  = (float(*)[TT])(un_raw + 4096);
    unsigned char* e_sh = un_raw;
    int tid = threadIdx.x;
    int lane = tid & 63, w = tid >> 6;

    for (int idx = tid; idx < TT*16; idx += 512) {
        int r = idx >> 4, q4 = (idx & 15) * 4;
        size_t goff = ((size_t)(b*TT + r))*DD + h*DH + q4;
        float4 kv = *(const float4*)&Kg[goff];
        K_sh[q4  ][r] = kv.x; K_sh[q4+1][r] = kv.y;
        K_sh[q4+2][r] = kv.z; K_sh[q4+3][r] = kv.w;
        float4 vv = *(const float4*)&Vg[goff];
        *(float4*)&V_sh[r][q4] = vv;
    }
    for (int idx = tid; idx < (TT*TT)/4; idx += 512) {
        int4 v = ((const int4*)(et + (size_t)b*TT*TT))[idx];
        unsigned pk = (unsigned)v.x | ((unsigned)v.y << 8) | ((unsigned)v.z << 16) | ((unsigned)v.w << 24);
        *(unsigned*)&e_sh[idx*4] = pk;
    }
    __syncthreads();
    if (tid < TT) {
        unsigned lo32 = 0, hi32 = 0;
        int iend = lo + TT/2;
        for (int i = 0; i < iend; ++i) {
            int r = e_sh[i*TT + tid];
            if (r < 4) lo32 += 1u << (8*r); else hi32 += 1u << (8*(r-4));
            if (i >= lo) cnt_sh[i - lo][tid] = make_uint2(lo32, hi32);
        }
    }
    __syncthreads();
    if (tid < 128) {
        int r = tid >> 4, q4 = (tid & 15) * 4;
        *(float4*)&rel_sh[r][q4] = *(const float4*)&rel[r*DD + h*DH + q4];
    }
    __syncthreads();

    auto processRow = [&](float q, int ii) {
        int i = lo + ii;
        size_t rowoff = (size_t)(b*TT + i);
        float crd[8]; dec8(cnt_sh[ii][i], crd);
        float a = q;
        #pragma unroll
        for (int r = 0; r < 8; ++r) a += crd[r]*rel_sh[r][lane];
        a_row[w][lane] = a;
        float arr[8];
        #pragma unroll
        for (int r = 0; r < 8; ++r) {
            float pr = a * rel_sh[r][lane];
            #pragma unroll
            for (int off = 32; off; off >>= 1) pr += __shfl_xor(pr, off);
            arr[r] = pr;
        }
        float s1;
        {
            int t = lane;
            float s = 0.0f;
            #pragma unroll
            for (int d0 = 0; d0 < DH; d0 += 4) {
                float4 av = *(const float4*)&a_row[w][d0];
                s += av.x*K_sh[d0][t] + av.y*K_sh[d0+1][t]
                   + av.z*K_sh[d0+2][t] + av.w*K_sh[d0+3][t];
            }
            float cr2[8]; dec8(cnt_sh[ii][t], cr2);
            float s2v = cr2[0]*arr[0] + cr2[1]*arr[1] + cr2[2]*arr[2] + cr2[3]*arr[3]
                      + cr2[4]*arr[4] + cr2[5]*arr[5] + cr2[6]*arr[6] + cr2[7]*arr[7];
            int m = mask[rowoff*TT + t];
            s1 = (m == 0) ? -1e9f : (s + s2v)*0.125f;
        }
        float s2 = -1e30f;
        if (lane < TT - DH) {
            int t = DH + lane;
            float s = 0.0f;
            #pragma unroll
            for (int d0 = 0; d0 < DH; d0 += 4) {
                float4 av = *(const float4*)&a_row[w][d0];
                s += av.x*K_sh[d0][t] + av.y*K_sh[d0+1][t]
                   + av.z*K_sh[d0+2][t] + av.w*K_sh[d0+3][t];
            }
            float cr2[8]; dec8(cnt_sh[ii][t], cr2);
            float s2v = cr2[0]*arr[0] + cr2[1]*arr[1] + cr2[2]*arr[2] + cr2[3]*arr[3]
                      + cr2[4]*arr[4] + cr2[5]*arr[5] + cr2[6]*arr[6] + cr2[7]*arr[7];
            int m = mask[rowoff*TT + t];
            s2 = (m == 0) ? -1e9f : (s + s2v)*0.125f;
        }
        float mx = fmaxf(s1, s2);
        #pragma unroll
        for (int off = 32; off; off >>= 1) mx = fmaxf(mx, __shfl_xor(mx, off));
        float e1 = __expf(s1 - mx);
        float e2 = (lane < TT - DH) ? __expf(s2 - mx) : 0.0f;
        float sm = e1 + e2;
        #pragma unroll
        for (int off = 32; off; off >>= 1) sm += __shfl_xor(sm, off);
        float inv = 1.0f / sm;
        p_row[w][lane] = e1 * inv;
        if (lane < TT - DH) p_row[w][DH + lane] = e2 * inv;
        float o = 0.0f;
        #pragma unroll 8
        for (int t = 0; t < TT; ++t) o += p_row[w][t] * V_sh[t][lane];
        out[rowoff*DD + h*DH + lane] = o;
    };

    // batch-prefetch all Q rows for this wave (static indexing, rule #20)
    float qv0, qv1, qv2, qv3, qv4 = 0.0f;
    {
        size_t base = ((size_t)(b*TT + lo + w))*DD + h*DH + lane;
        qv0 = Qb[base];
        qv1 = Qb[base + (size_t)8*DD];
        qv2 = Qb[base + (size_t)16*DD];
        qv3 = Qb[base + (size_t)24*DD];
        if (w < 4) qv4 = Qb[base + (size_t)32*DD];
    }
    processRow(qv0, w);
    processRow(qv1, w + 8);
    processRow(qv2, w + 16);
    processRow(qv3, w + 24);
    if (w < 4) processRow(qv4, w + 32);
}

// ---------------------------------------------------------------------------
// Merged epilogue: output splits + delta(bf16) + strategy/emotion logits
__global__ __launch_bounds__(256) void k_finlog(const float* __restrict__ outs,
        const float* __restrict__ sem_cls,
        const float* __restrict__ strW, const float* __restrict__ strB,
        const float* __restrict__ emoW, const float* __restrict__ emoB,
        float* __restrict__ o_last_stra, float* __restrict__ o_emo,
        float* __restrict__ o_last_delta, float* __restrict__ o_str,
        float* __restrict__ o_emo_log, unsigned short* __restrict__ deltaB)
{
    __shared__ float part[14][16];
    int bid = blockIdx.x; int b = bid / UU, u = bid % UU;
    const float* sem = outs + ((size_t)(b*TT + 3*u))*DD;
    const float* st  = sem + DD;
    const float* em  = st + DD;
    const float* sc  = sem_cls + ((size_t)(b*UU + u))*DD;
    unsigned short* de = deltaB + ((size_t)(b*UU + u))*DD;
    float* oe = o_emo + ((size_t)(b*UU + u))*DD;
    int t = threadIdx.x;
    for (int d = t; d < DD; d += 256) {
        float dl = sem[d] - sc[d];
        de[d] = f2b(dl); oe[d] = em[d];
        if (u == UU-1) { o_last_stra[b*DD + d] = st[d]; o_last_delta[b*DD + d] = dl; }
    }
    if (t < 224) {
        int o = t >> 4, c = t & 15;
        float s = 0.0f;
        if (o < 8) {
            for (int d = c*64; d < c*64 + 64; ++d) s += st[d]*strW[d*8 + o];
        } else {
            int j = o - 8;
            for (int d = c*64; d < c*64 + 64; ++d) s += em[d]*emoW[d*6 + j];
        }
        part[o][c] = s;
    }
    __syncthreads();
    if (t < 14) {
        float s = 0.0f;
        #pragma unroll
        for (int c2 = 0; c2 < 16; ++c2) s += part[t][c2];
        if (t < 8) o_str[(b*UU + u)*8 + t] = s + strB[t];
        else       o_emo_log[(b*UU + u)*6 + (t-8)] = s + emoB[t-8];
    }
}

// ---------------------------------------------------------------------------
extern "C" void kernel_launch(void* const* d_in, const int* in_sizes, int n_in,
                              void* d_out, int out_size, void* d_ws, size_t ws_size,
                              hipStream_t stream)
{
    const float* hidden  = (const float*)d_in[0];
    const float* emo_csk = (const float*)d_in[1];
    const float* Wq  = (const float*)d_in[2];
    const float* bq  = (const float*)d_in[3];
    const float* Wk  = (const float*)d_in[4];
    const float* bk  = (const float*)d_in[5];
    const float* Wv  = (const float*)d_in[6];
    const float* bv  = (const float*)d_in[7];
    const float* rel = (const float*)d_in[8];
    const float* fusW = (const float*)d_in[9];
    const float* fusB = (const float*)d_in[10];
    const float* bng = (const float*)d_in[11];
    const float* bnb = (const float*)d_in[12];
    const float* bnm = (const float*)d_in[13];
    const float* bnv = (const float*)d_in[14];
    const float* cskW = (const float*)d_in[15];
    const float* cskB = (const float*)d_in[16];
    const float* emoW = (const float*)d_in[17];
    const float* emoB = (const float*)d_in[18];
    const float* strW = (const float*)d_in[19];
    const float* strB = (const float*)d_in[20];
    const float* bowW = (const float*)d_in[21];
    const int* clsIdx = (const int*)d_in[22];
    const int* tGraph = (const int*)d_in[23];
    const int* iGraph = (const int*)d_in[24];
    const int* tEdge  = (const int*)d_in[25];
    const int* iEdge  = (const int*)d_in[26];

    float* out = (float*)d_out;
    float* o_last_stra  = out;             // B*D          = 8192
    float* o_emo_trans  = out + 8192;      // B*U*D        = 196608
    float* o_last_delta = out + 204800;    // B*D          = 8192
    float* o_sem_cls    = out + 212992;    // B*U*D        = 196608
    float* o_str_log    = out + 409600;    // B*U*8        = 1536
    float* o_emo_log    = out + 411136;    // B*U*6        = 1152
    float* o_bow        = out + 412288;    // B*U*VOCAB

    float* ws = (float*)d_ws;
    const int SZ_BTD = BB*TT*DD;   // 589824
    const int SZ_BUD = BB*UU*DD;   // 196608
    float* trans_in  = ws;
    float* Qb        = trans_in + SZ_BTD;
    float* Kb        = Qb + SZ_BTD;
    float* Vb        = Kb + SZ_BTD;
    float* trans_out = Vb + SZ_BTD;
    float* inter_out = trans_out + SZ_BTD;
    float* outsB     = inter_out + SZ_BTD;
    float* csk_norm  = outsB + SZ_BTD;
    unsigned short* deltaB = (unsigned short*)(csk_norm + SZ_BUD);

    // 1. gather cls + batchnorm (merged, grid-split)
    k_gather_bn<<<dim3(BB*UU + (BB*UU*CSKN+255)/256), dim3(256), 0, stream>>>(
            hidden, clsIdx, o_sem_cls, trans_in, emo_csk, bng, bnb, bnm, bnv, csk_norm);
    // 2. csk_proj GEMM fused with scatter-add into trans_in[:,2::3]
    mm64<4><<<dim3(16, 3), dim3(256), 0, stream>>>(csk_norm, nullptr, CSKN, cskW, cskB,
            nullptr, nullptr, trans_in, DD, CSKN);

    auto attention = [&](const float* x, const int* graph, const int* edge, float* ctx_out) {
        mm_qkv<<<dim3(24, (BB*TT)/64), dim3(256), 0, stream>>>(x, Wq, Wk, Wv, bq, bk, bv, Qb, Kb, Vb);
        k_attn<<<dim3(BB*HH*2), dim3(512), 0, stream>>>(Qb, Kb, Vb, edge, rel, graph, ctx_out);
    };
    attention(trans_in, tGraph, tEdge, trans_out);
    attention(trans_out, iGraph, iEdge, inter_out);

    // fusion gate + blend fused: outsB = g*trans + (1-g)*inter
    mm64<3><<<dim3(16, (BB*TT)/64), dim3(256), 0, stream>>>(trans_out, inter_out, DD, fusW, fusB,
            trans_out, inter_out, outsB, DD, 2*DD);

    // merged epilogue (writes deltaB bf16 + small logits)
    k_finlog<<<dim3(BB*UU), dim3(256), 0, stream>>>(outsB, o_sem_cls, strW, strB, emoW, emoB,
            o_last_stra, o_emo_trans, o_last_delta, o_str_log, o_emo_log, deltaB);

    // bow_logits = delta @ bow_W (barrier-amortized)
    mm_bow<<<dim3((NVOCAB+63)/64), dim3(256), 0, stream>>>(deltaB, bowW, o_bow);
}

// Round 14
// 263.477 us; speedup vs baseline: 1.4845x; 1.0450x over previous
//
#include <hip/hip_runtime.h>
#include <math.h>

// Problem constants
#define BB 8
#define LL 512
#define UU 24
#define DD 1024
#define HH 16
#define DH 64
#define TT 72
#define CSKN 1024
#define NVOCAB 54945

typedef __attribute__((ext_vector_type(8))) short bf16x8;
typedef __attribute__((ext_vector_type(4))) float f32x4;

__device__ inline unsigned short f2b(float x) {
    unsigned u = __float_as_uint(x);
    unsigned r = u + 0x7FFFu + ((u >> 16) & 1u);
    return (unsigned short)(r >> 16);
}
__device__ inline unsigned pack2(float lo, float hi) {
    return (unsigned)f2b(lo) | ((unsigned)f2b(hi) << 16);
}
__device__ inline void dec8(uint2 c, float* cr) {
    cr[0] = (float)( c.x        & 0xff); cr[1] = (float)((c.x >>  8) & 0xff);
    cr[2] = (float)((c.x >> 16) & 0xff); cr[3] = (float)((c.x >> 24) & 0xff);
    cr[4] = (float)( c.y        & 0xff); cr[5] = (float)((c.y >>  8) & 0xff);
    cr[6] = (float)((c.y >> 16) & 0xff); cr[7] = (float)((c.y >> 24) & 0xff);
}

// ---------------------------------------------------------------------------
// Merged: gather cls (blocks 0..191) + batchnorm (blocks 192..959)
__global__ __launch_bounds__(256) void k_gather_bn(const float* __restrict__ hidden,
        const int* __restrict__ idx, float* __restrict__ sem_cls, float* __restrict__ trans_in,
        const float* __restrict__ x, const float* __restrict__ g,
        const float* __restrict__ be, const float* __restrict__ mu,
        const float* __restrict__ var, float* __restrict__ y)
{
    int bid = blockIdx.x;
    if (bid < BB*UU) {
        int b = bid / UU, u = bid % UU;
        int row = idx[b*UU + u];
        const float* src = hidden + ((size_t)(b*LL + row))*DD;
        float* d0 = trans_in + ((size_t)(b*TT + 3*u))*DD;
        float* sc = sem_cls + ((size_t)(b*UU + u))*DD;
        for (int d = threadIdx.x; d < DD; d += 256) {
            float v = src[d];
            sc[d] = v;
            d0[d] = v; d0[DD + d] = v; d0[2*DD + d] = v;
        }
    } else {
        int i = (bid - BB*UU)*256 + threadIdx.x;
        int n = BB*UU*CSKN;
        if (i < n) {
            int c = i % CSKN;
            y[i] = (x[i] - mu[c]) * (1.0f/sqrtf(var[c] + 1e-5f)) * g[c] + be[c];
        }
    }
}

// ---------------------------------------------------------------------------
// MFMA bf16 GEMM, 64x64 tile, BK=64 double-buffered.
// EPI 4 = csk scatter-add into trans_in[:,2::3] (skip u==U-1).
// EPI 5 = fusion: v=sigmoid-gate blend of ep1/ep2, write C=outsB AND all
//         elementwise output splits (deltaB bf16, o_emo, o_last_*).
template<int EPI>
__global__ __launch_bounds__(256) void mm64(
        const float* __restrict__ A1, const float* __restrict__ A2, int K1,
        const float* __restrict__ Bm, const float* __restrict__ bias,
        const float* __restrict__ ep1, const float* __restrict__ ep2,
        float* __restrict__ C, int N, int K,
        const float* __restrict__ sem_cls, unsigned short* __restrict__ deltaB,
        float* __restrict__ o_emo, float* __restrict__ o_lstra,
        float* __restrict__ o_ldelta)
{
    __shared__ __align__(16) unsigned short As[2][64][72];
    __shared__ __align__(16) unsigned short Bs[2][64][72];
    int tid = threadIdx.x;
    int wave = tid >> 6, lane = tid & 63;
    int l16 = lane & 15, g = lane >> 4;
    int wm = wave & 1, wn = wave >> 1;
    int row0 = blockIdx.y * 64, col0 = blockIdx.x * 64;

    int ar = tid >> 2, akq = (tid & 3) * 16;
    int bj0 = (tid & 31) * 2, kp = tid >> 5;
    float4 a0, a1, a2, a3;
    float2 b0[4], b1[4];

    auto loadT = [&](int k0) {
        int kk = k0 + akq;
        const float* src = (kk < K1) ? A1 + (size_t)(row0+ar)*K1 + kk
                                     : A2 + (size_t)(row0+ar)*(K-K1) + (kk-K1);
        a0 = *(const float4*)src;      a1 = *(const float4*)(src+4);
        a2 = *(const float4*)(src+8);  a3 = *(const float4*)(src+12);
        #pragma unroll
        for (int s = 0; s < 4; ++s) {
            int kb = 2*(kp + 8*s);
            const float* bp = Bm + (size_t)(k0 + kb)*N + col0 + bj0;
            b0[s] = *(const float2*)bp;
            b1[s] = *(const float2*)(bp + N);
        }
    };
    auto storeT = [&](int buf) {
        unsigned* da = (unsigned*)&As[buf][ar][akq];
        da[0]=pack2(a0.x,a0.y); da[1]=pack2(a0.z,a0.w);
        da[2]=pack2(a1.x,a1.y); da[3]=pack2(a1.z,a1.w);
        da[4]=pack2(a2.x,a2.y); da[5]=pack2(a2.z,a2.w);
        da[6]=pack2(a3.x,a3.y); da[7]=pack2(a3.z,a3.w);
        #pragma unroll
        for (int s = 0; s < 4; ++s) {
            int kb = 2*(kp + 8*s);
            *(unsigned*)&Bs[buf][bj0  ][kb] = pack2(b0[s].x, b1[s].x);
            *(unsigned*)&Bs[buf][bj0+1][kb] = pack2(b0[s].y, b1[s].y);
        }
    };

    f32x4 acc[2][2] = {};
    loadT(0); storeT(0);
    __syncthreads();
    int nt = K / 64;
    for (int t = 0; t < nt; ++t) {
        int cur = t & 1;
        if (t + 1 < nt) loadT((t+1)*64);
        #pragma unroll
        for (int kk = 0; kk < 2; ++kk) {
            bf16x8 af[2], bfr[2];
            #pragma unroll
            for (int mf = 0; mf < 2; ++mf) af[mf] = *(const bf16x8*)&As[cur][wm*32 + mf*16 + l16][kk*32 + g*8];
            #pragma unroll
            for (int nf = 0; nf < 2; ++nf) bfr[nf] = *(const bf16x8*)&Bs[cur][wn*32 + nf*16 + l16][kk*32 + g*8];
            #pragma unroll
            for (int mf = 0; mf < 2; ++mf)
                #pragma unroll
                for (int nf = 0; nf < 2; ++nf)
                    acc[mf][nf] = __builtin_amdgcn_mfma_f32_16x16x32_bf16(af[mf], bfr[nf], acc[mf][nf], 0, 0, 0);
        }
        if (t + 1 < nt) storeT(cur ^ 1);
        __syncthreads();
    }
    #pragma unroll
    for (int mf = 0; mf < 2; ++mf)
        #pragma unroll
        for (int nf = 0; nf < 2; ++nf) {
            int cc = col0 + wn*32 + nf*16 + l16;
            float bv = bias[cc];
            #pragma unroll
            for (int r = 0; r < 4; ++r) {
                int rr = row0 + wm*32 + mf*16 + g*4 + r;
                float v = acc[mf][nf][r] + bv;
                if (EPI == 4) {
                    int bq = rr / UU, uq = rr % UU;
                    if (uq < UU-1) {
                        float* dst = &C[((size_t)(bq*TT + 3*uq + 2))*DD + cc];
                        *dst += v;
                    }
                } else { // EPI == 5: gate blend + all elementwise splits
                    float gg = 1.0f/(1.0f + __expf(-v));
                    float tv = ep1[(size_t)rr*N + cc];
                    float iv = ep2[(size_t)rr*N + cc];
                    float bl = gg*tv + (1.0f - gg)*iv;
                    C[(size_t)rr*N + cc] = bl;
                    int b = rr / TT, tt = rr % TT;
                    int m3 = tt % 3, u = tt / 3;
                    if (m3 == 0) {
                        float dl = bl - sem_cls[((size_t)(b*UU + u))*DD + cc];
                        deltaB[((size_t)(b*UU + u))*DD + cc] = f2b(dl);
                        if (u == UU-1) o_ldelta[b*DD + cc] = dl;
                    } else if (m3 == 1) {
                        if (u == UU-1) o_lstra[b*DD + cc] = bl;
                    } else {
                        o_emo[((size_t)(b*UU + u))*DD + cc] = bl;
                    }
                }
            }
        }
}

// ---------------------------------------------------------------------------
// Fused Q/K/V projection, BM=64 BN=64, BK=64 dbuf. Grid (48, 9);
// blockIdx.x>>4 selects Q/K/V; 432 blocks (~1.7/CU) for latency overlap.
__global__ __launch_bounds__(256) void mm_qkv(
        const float* __restrict__ x,
        const float* __restrict__ W0, const float* __restrict__ W1, const float* __restrict__ W2,
        const float* __restrict__ v0, const float* __restrict__ v1, const float* __restrict__ v2,
        float* __restrict__ C0, float* __restrict__ C1, float* __restrict__ C2)
{
    __shared__ __align__(16) unsigned short As[2][64][72];
    __shared__ __align__(16) unsigned short Bs[2][64][72];
    int which = blockIdx.x >> 4;
    int col0 = (blockIdx.x & 15) * 64;
    int row0 = blockIdx.y * 64;
    const float* W  = (which == 0) ? W0 : (which == 1) ? W1 : W2;
    const float* bb = (which == 0) ? v0 : (which == 1) ? v1 : v2;
    float*       C  = (which == 0) ? C0 : (which == 1) ? C1 : C2;
    int tid = threadIdx.x;
    int wave = tid >> 6, lane = tid & 63;
    int l16 = lane & 15, g = lane >> 4;
    int wm = wave & 1, wn = wave >> 1;

    int ar = tid >> 2, akq = (tid & 3) * 16;
    int bj0 = (tid & 31) * 2, kp = tid >> 5;
    float4 a0, a1, a2, a3;
    float2 b0[4], b1[4];

    auto loadT = [&](int k0) {
        const float* src = x + (size_t)(row0+ar)*DD + k0 + akq;
        a0 = *(const float4*)src;      a1 = *(const float4*)(src+4);
        a2 = *(const float4*)(src+8);  a3 = *(const float4*)(src+12);
        #pragma unroll
        for (int s = 0; s < 4; ++s) {
            int kb = 2*(kp + 8*s);
            const float* bp = W + (size_t)(k0 + kb)*DD + col0 + bj0;
            b0[s] = *(const float2*)bp;
            b1[s] = *(const float2*)(bp + DD);
        }
    };
    auto storeT = [&](int buf) {
        unsigned* da = (unsigned*)&As[buf][ar][akq];
        da[0]=pack2(a0.x,a0.y); da[1]=pack2(a0.z,a0.w);
        da[2]=pack2(a1.x,a1.y); da[3]=pack2(a1.z,a1.w);
        da[4]=pack2(a2.x,a2.y); da[5]=pack2(a2.z,a2.w);
        da[6]=pack2(a3.x,a3.y); da[7]=pack2(a3.z,a3.w);
        #pragma unroll
        for (int s = 0; s < 4; ++s) {
            int kb = 2*(kp + 8*s);
            *(unsigned*)&Bs[buf][bj0  ][kb] = pack2(b0[s].x, b1[s].x);
            *(unsigned*)&Bs[buf][bj0+1][kb] = pack2(b0[s].y, b1[s].y);
        }
    };

    f32x4 acc[2][2] = {};
    loadT(0); storeT(0);
    __syncthreads();
    for (int t = 0; t < 16; ++t) {
        int cur = t & 1;
        if (t < 15) loadT((t+1)*64);
        #pragma unroll
        for (int kk = 0; kk < 2; ++kk) {
            bf16x8 af[2], bfr[2];
            #pragma unroll
            for (int mf = 0; mf < 2; ++mf) af[mf] = *(const bf16x8*)&As[cur][wm*32 + mf*16 + l16][kk*32 + g*8];
            #pragma unroll
            for (int nf = 0; nf < 2; ++nf) bfr[nf] = *(const bf16x8*)&Bs[cur][wn*32 + nf*16 + l16][kk*32 + g*8];
            #pragma unroll
            for (int mf = 0; mf < 2; ++mf)
                #pragma unroll
                for (int nf = 0; nf < 2; ++nf)
                    acc[mf][nf] = __builtin_amdgcn_mfma_f32_16x16x32_bf16(af[mf], bfr[nf], acc[mf][nf], 0, 0, 0);
        }
        if (t < 15) storeT(cur ^ 1);
        __syncthreads();
    }
    #pragma unroll
    for (int mf = 0; mf < 2; ++mf)
        #pragma unroll
        for (int nf = 0; nf < 2; ++nf) {
            int cc = col0 + wn*32 + nf*16 + l16;
            float bv = bb[cc];
            #pragma unroll
            for (int r = 0; r < 4; ++r) {
                int rr = row0 + wm*32 + mf*16 + g*4 + r;
                C[(size_t)rr*DD + cc] = acc[mf][nf][r] + bv;
            }
        }
}

// ---------------------------------------------------------------------------
// bow GEMM (R11, best measured): deltaB(bf16)[192,1024] @ bowW -> o_bow.
// Barriers every 4 k-steps; B direct from global with 4-deep prefetch.
__global__ __launch_bounds__(256, 1) void mm_bow(
        const unsigned short* __restrict__ Ab, const float* __restrict__ Bm,
        float* __restrict__ C)
{
    __shared__ __align__(16) unsigned short A_lds[192][136];   // 52.2 KB
    const int N = NVOCAB;
    int tid = threadIdx.x;
    int lane = tid & 63, wave = tid >> 6;
    int l16 = lane & 15, g = lane >> 4;
    int col = blockIdx.x * 64 + wave * 16 + l16;
    int colc = (col < N) ? col : (N - 1);
    const float* bbase = Bm + (size_t)(g * 8) * N + colc;

    int4 areg0, areg1, areg2, areg3, areg4, areg5, areg6, areg7, areg8, areg9, areg10, areg11;
#define AIDX(i) int r##i = ((i)*256 + tid) >> 4, c##i = (((i)*256 + tid) & 15) * 8
    AIDX(0); AIDX(1); AIDX(2); AIDX(3); AIDX(4); AIDX(5);
    AIDX(6); AIDX(7); AIDX(8); AIDX(9); AIDX(10); AIDX(11);
#undef AIDX
#define LOADA(s) {                                                             \
        const unsigned short* ab = Ab + (s)*128;                               \
        areg0  = *(const int4*)(ab + (size_t)r0*DD  + c0);                     \
        areg1  = *(const int4*)(ab + (size_t)r1*DD  + c1);                     \
        areg2  = *(const int4*)(ab + (size_t)r2*DD  + c2);                     \
        areg3  = *(const int4*)(ab + (size_t)r3*DD  + c3);                     \
        areg4  = *(const int4*)(ab + (size_t)r4*DD  + c4);                     \
        areg5  = *(const int4*)(ab + (size_t)r5*DD  + c5);                     \
        areg6  = *(const int4*)(ab + (size_t)r6*DD  + c6);                     \
        areg7  = *(const int4*)(ab + (size_t)r7*DD  + c7);                     \
        areg8  = *(const int4*)(ab + (size_t)r8*DD  + c8);                     \
        areg9  = *(const int4*)(ab + (size_t)r9*DD  + c9);                     \
        areg10 = *(const int4*)(ab + (size_t)r10*DD + c10);                    \
        areg11 = *(const int4*)(ab + (size_t)r11*DD + c11);                    \
    }
#define WRITEA() {                                                             \
        *(int4*)&A_lds[r0][c0]   = areg0;  *(int4*)&A_lds[r1][c1]   = areg1;   \
        *(int4*)&A_lds[r2][c2]   = areg2;  *(int4*)&A_lds[r3][c3]   = areg3;   \
        *(int4*)&A_lds[r4][c4]   = areg4;  *(int4*)&A_lds[r5][c5]   = areg5;   \
        *(int4*)&A_lds[r6][c6]   = areg6;  *(int4*)&A_lds[r7][c7]   = areg7;   \
        *(int4*)&A_lds[r8][c8]   = areg8;  *(int4*)&A_lds[r9][c9]   = areg9;   \
        *(int4*)&A_lds[r10][c10] = areg10; *(int4*)&A_lds[r11][c11] = areg11;  \
    }

    f32x4 acc[12] = {};
    float bs[4][8];

#define LOADB(dst, t_) { const float* bp = bbase + (size_t)(t_) * 32 * N;      \
        _Pragma("unroll") for (int j = 0; j < 8; ++j) dst[j] = bp[(size_t)j * N]; }
#define PACKB(fr, sv) { _Pragma("unroll") for (int j = 0; j < 8; ++j)          \
        ((unsigned short*)&fr)[j] = f2b(sv[j]); }

    LOADA(0); WRITEA();
    #pragma unroll
    for (int p = 0; p < 4; ++p) LOADB(bs[p], p);
    __syncthreads();

    for (int s = 0; s < 8; ++s) {
        if (s < 7) LOADA(s + 1);
        #pragma unroll
        for (int p = 0; p < 4; ++p) {
            int P = s*4 + p;
            bf16x8 fr;
            PACKB(fr, bs[p]);
            if (P + 4 < 32) LOADB(bs[p], P + 4);
            #pragma unroll
            for (int mf = 0; mf < 12; ++mf) {
                bf16x8 af = *(const bf16x8*)&A_lds[mf*16 + l16][p*32 + g*8];
                acc[mf] = __builtin_amdgcn_mfma_f32_16x16x32_bf16(af, fr, acc[mf], 0, 0, 0);
            }
        }
        if (s < 7) {
            __syncthreads();
            WRITEA();
            __syncthreads();
        }
    }
#undef LOADA
#undef WRITEA
#undef LOADB
#undef PACKB
    if (col < N) {
        #pragma unroll
        for (int mf = 0; mf < 12; ++mf)
            #pragma unroll
            for (int r = 0; r < 4; ++r)
                C[(size_t)(mf * 16 + g * 4 + r) * N + col] = acc[mf][r];
    }
}

// ---------------------------------------------------------------------------
// Fully fused attention per (b,h,half): edge prefix in-block, prep + scores +
// softmax + PV. 256 blocks, 512 thr. Q rows batch-prefetched.
__global__ __launch_bounds__(512) void k_attn(const float* __restrict__ Qb,
        const float* __restrict__ Kg, const float* __restrict__ Vg,
        const int* __restrict__ et, const float* __restrict__ rel,
        const int* __restrict__ mask, float* __restrict__ out)
{
    int bid = blockIdx.x;
    int is = bid & 1;
    int h  = (bid >> 1) & (HH-1);
    int b  = bid >> 5;
    int lo = is * (TT/2);
    __shared__ float K_sh[DH][TT+1];
    __shared__ float V_sh[TT][DH];
    __shared__ uint2 cnt_sh[TT/2][TT];
    __shared__ __align__(16) unsigned char un_raw[6400];
    float (*rel_sh)[DH] = (float(*)[DH])un_raw;
    float (*a_row)[DH]  = (float(*)[DH])(un_raw + 2048);
    float (*p_row)[TT]  = (float(*)[TT])(un_raw + 4096);
    unsigned char* e_sh = un_raw;
    int tid = threadIdx.x;
    int lane = tid & 63, w = tid >> 6;

    for (int idx = tid; idx < TT*16; idx += 512) {
        int r = idx >> 4, q4 = (idx & 15) * 4;
        size_t goff = ((size_t)(b*TT + r))*DD + h*DH + q4;
        float4 kv = *(const float4*)&Kg[goff];
        K_sh[q4  ][r] = kv.x; K_sh[q4+1][r] = kv.y;
        K_sh[q4+2][r] = kv.z; K_sh[q4+3][r] = kv.w;
        float4 vv = *(const float4*)&Vg[goff];
        *(float4*)&V_sh[r][q4] = vv;
    }
    for (int idx = tid; idx < (TT*TT)/4; idx += 512) {
        int4 v = ((const int4*)(et + (size_t)b*TT*TT))[idx];
        unsigned pk = (unsigned)v.x | ((unsigned)v.y << 8) | ((unsigned)v.z << 16) | ((unsigned)v.w << 24);
        *(unsigned*)&e_sh[idx*4] = pk;
    }
    __syncthreads();
    if (tid < TT) {
        unsigned lo32 = 0, hi32 = 0;
        int iend = lo + TT/2;
        for (int i = 0; i < iend; ++i) {
            int r = e_sh[i*TT + tid];
            if (r < 4) lo32 += 1u << (8*r); else hi32 += 1u << (8*(r-4));
            if (i >= lo) cnt_sh[i - lo][tid] = make_uint2(lo32, hi32);
        }
    }
    __syncthreads();
    if (tid < 128) {
        int r = tid >> 4, q4 = (tid & 15) * 4;
        *(float4*)&rel_sh[r][q4] = *(const float4*)&rel[r*DD + h*DH + q4];
    }
    __syncthreads();

    auto processRow = [&](float q, int ii) {
        int i = lo + ii;
        size_t rowoff = (size_t)(b*TT + i);
        float crd[8]; dec8(cnt_sh[ii][i], crd);
        float a = q;
        #pragma unroll
        for (int r = 0; r < 8; ++r) a += crd[r]*rel_sh[r][lane];
        a_row[w][lane] = a;
        float arr[8];
        #pragma unroll
        for (int r = 0; r < 8; ++r) {
            float pr = a * rel_sh[r][lane];
            #pragma unroll
            for (int off = 32; off; off >>= 1) pr += __shfl_xor(pr, off);
            arr[r] = pr;
        }
        float s1;
        {
            int t = lane;
            float s = 0.0f;
            #pragma unroll
            for (int d0 = 0; d0 < DH; d0 += 4) {
                float4 av = *(const float4*)&a_row[w][d0];
                s += av.x*K_sh[d0][t] + av.y*K_sh[d0+1][t]
                   + av.z*K_sh[d0+2][t] + av.w*K_sh[d0+3][t];
            }
            float cr2[8]; dec8(cnt_sh[ii][t], cr2);
            float s2v = cr2[0]*arr[0] + cr2[1]*arr[1] + cr2[2]*arr[2] + cr2[3]*arr[3]
                      + cr2[4]*arr[4] + cr2[5]*arr[5] + cr2[6]*arr[6] + cr2[7]*arr[7];
            int m = mask[rowoff*TT + t];
            s1 = (m == 0) ? -1e9f : (s + s2v)*0.125f;
        }
        float s2 = -1e30f;
        if (lane < TT - DH) {
            int t = DH + lane;
            float s = 0.0f;
            #pragma unroll
            for (int d0 = 0; d0 < DH; d0 += 4) {
                float4 av = *(const float4*)&a_row[w][d0];
                s += av.x*K_sh[d0][t] + av.y*K_sh[d0+1][t]
                   + av.z*K_sh[d0+2][t] + av.w*K_sh[d0+3][t];
            }
            float cr2[8]; dec8(cnt_sh[ii][t], cr2);
            float s2v = cr2[0]*arr[0] + cr2[1]*arr[1] + cr2[2]*arr[2] + cr2[3]*arr[3]
                      + cr2[4]*arr[4] + cr2[5]*arr[5] + cr2[6]*arr[6] + cr2[7]*arr[7];
            int m = mask[rowoff*TT + t];
            s2 = (m == 0) ? -1e9f : (s + s2v)*0.125f;
        }
        float mx = fmaxf(s1, s2);
        #pragma unroll
        for (int off = 32; off; off >>= 1) mx = fmaxf(mx, __shfl_xor(mx, off));
        float e1 = __expf(s1 - mx);
        float e2 = (lane < TT - DH) ? __expf(s2 - mx) : 0.0f;
        float sm = e1 + e2;
        #pragma unroll
        for (int off = 32; off; off >>= 1) sm += __shfl_xor(sm, off);
        float inv = 1.0f / sm;
        p_row[w][lane] = e1 * inv;
        if (lane < TT - DH) p_row[w][DH + lane] = e2 * inv;
        float o = 0.0f;
        #pragma unroll 8
        for (int t = 0; t < TT; ++t) o += p_row[w][t] * V_sh[t][lane];
        out[rowoff*DD + h*DH + lane] = o;
    };

    float qv0, qv1, qv2, qv3, qv4 = 0.0f;
    {
        size_t base = ((size_t)(b*TT + lo + w))*DD + h*DH + lane;
        qv0 = Qb[base];
        qv1 = Qb[base + (size_t)8*DD];
        qv2 = Qb[base + (size_t)16*DD];
        qv3 = Qb[base + (size_t)24*DD];
        if (w < 4) qv4 = Qb[base + (size_t)32*DD];
    }
    processRow(qv0, w);
    processRow(qv1, w + 8);
    processRow(qv2, w + 16);
    processRow(qv3, w + 24);
    if (w < 4) processRow(qv4, w + 32);
}

// ---------------------------------------------------------------------------
// strategy (8) and emotion (6) logits only (elementwise splits moved to EPI=5)
__global__ __launch_bounds__(256) void k_logits(const float* __restrict__ outs,
        const float* __restrict__ strW, const float* __restrict__ strB,
        const float* __restrict__ emoW, const float* __restrict__ emoB,
        float* __restrict__ o_str, float* __restrict__ o_emo_log)
{
    __shared__ float part[14][16];
    int bid = blockIdx.x; int b = bid / UU, u = bid % UU;
    const float* st = outs + ((size_t)(b*TT + 3*u + 1))*DD;
    const float* em = st + DD;
    int t = threadIdx.x;
    if (t < 224) {
        int o = t >> 4, c = t & 15;
        float s = 0.0f;
        if (o < 8) {
            for (int d = c*64; d < c*64 + 64; ++d) s += st[d]*strW[d*8 + o];
        } else {
            int j = o - 8;
            for (int d = c*64; d < c*64 + 64; ++d) s += em[d]*emoW[d*6 + j];
        }
        part[o][c] = s;
    }
    __syncthreads();
    if (t < 14) {
        float s = 0.0f;
        #pragma unroll
        for (int c2 = 0; c2 < 16; ++c2) s += part[t][c2];
        if (t < 8) o_str[(b*UU + u)*8 + t] = s + strB[t];
        else       o_emo_log[(b*UU + u)*6 + (t-8)] = s + emoB[t-8];
    }
}

// ---------------------------------------------------------------------------
extern "C" void kernel_launch(void* const* d_in, const int* in_sizes, int n_in,
                              void* d_out, int out_size, void* d_ws, size_t ws_size,
                              hipStream_t stream)
{
    const float* hidden  = (const float*)d_in[0];
    const float* emo_csk = (const float*)d_in[1];
    const float* Wq  = (const float*)d_in[2];
    const float* bq  = (const float*)d_in[3];
    const float* Wk  = (const float*)d_in[4];
    const float* bk  = (const float*)d_in[5];
    const float* Wv  = (const float*)d_in[6];
    const float* bv  = (const float*)d_in[7];
    const float* rel = (const float*)d_in[8];
    const float* fusW = (const float*)d_in[9];
    const float* fusB = (const float*)d_in[10];
    const float* bng = (const float*)d_in[11];
    const float* bnb = (const float*)d_in[12];
    const float* bnm = (const float*)d_in[13];
    const float* bnv = (const float*)d_in[14];
    const float* cskW = (const float*)d_in[15];
    const float* cskB = (const float*)d_in[16];
    const float* emoW = (const float*)d_in[17];
    const float* emoB = (const float*)d_in[18];
    const float* strW = (const float*)d_in[19];
    const float* strB = (const float*)d_in[20];
    const float* bowW = (const float*)d_in[21];
    const int* clsIdx = (const int*)d_in[22];
    const int* tGraph = (const int*)d_in[23];
    const int* iGraph = (const int*)d_in[24];
    const int* tEdge  = (const int*)d_in[25];
    const int* iEdge  = (const int*)d_in[26];

    float* out = (float*)d_out;
    float* o_last_stra  = out;             // B*D          = 8192
    float* o_emo_trans  = out + 8192;      // B*U*D        = 196608
    float* o_last_delta = out + 204800;    // B*D          = 8192
    float* o_sem_cls    = out + 212992;    // B*U*D        = 196608
    float* o_str_log    = out + 409600;    // B*U*8        = 1536
    float* o_emo_log    = out + 411136;    // B*U*6        = 1152
    float* o_bow        = out + 412288;    // B*U*VOCAB

    float* ws = (float*)d_ws;
    const int SZ_BTD = BB*TT*DD;   // 589824
    const int SZ_BUD = BB*UU*DD;   // 196608
    float* trans_in  = ws;
    float* Qb        = trans_in + SZ_BTD;
    float* Kb        = Qb + SZ_BTD;
    float* Vb        = Kb + SZ_BTD;
    float* trans_out = Vb + SZ_BTD;
    float* inter_out = trans_out + SZ_BTD;
    float* outsB     = inter_out + SZ_BTD;
    float* csk_norm  = outsB + SZ_BTD;
    unsigned short* deltaB = (unsigned short*)(csk_norm + SZ_BUD);

    // 1. gather cls + batchnorm (merged, grid-split)
    k_gather_bn<<<dim3(BB*UU + (BB*UU*CSKN+255)/256), dim3(256), 0, stream>>>(
            hidden, clsIdx, o_sem_cls, trans_in, emo_csk, bng, bnb, bnm, bnv, csk_norm);
    // 2. csk_proj GEMM fused with scatter-add into trans_in[:,2::3]
    mm64<4><<<dim3(16, 3), dim3(256), 0, stream>>>(csk_norm, nullptr, CSKN, cskW, cskB,
            nullptr, nullptr, trans_in, DD, CSKN, nullptr, nullptr, nullptr, nullptr, nullptr);

    auto attention = [&](const float* x, const int* graph, const int* edge, float* ctx_out) {
        mm_qkv<<<dim3(48, (BB*TT)/64), dim3(256), 0, stream>>>(x, Wq, Wk, Wv, bq, bk, bv, Qb, Kb, Vb);
        k_attn<<<dim3(BB*HH*2), dim3(512), 0, stream>>>(Qb, Kb, Vb, edge, rel, graph, ctx_out);
    };
    attention(trans_in, tGraph, tEdge, trans_out);
    attention(trans_out, iGraph, iEdge, inter_out);

    // fusion gate + blend + ALL elementwise output splits (EPI=5)
    mm64<5><<<dim3(16, (BB*TT)/64), dim3(256), 0, stream>>>(trans_out, inter_out, DD, fusW, fusB,
            trans_out, inter_out, outsB, DD, 2*DD,
            o_sem_cls, deltaB, o_emo_trans, o_last_stra, o_last_delta);

    // strategy/emotion logits
    k_logits<<<dim3(BB*UU), dim3(256), 0, stream>>>(outsB, strW, strB, emoW, emoB,
            o_str_log, o_emo_log);

    // bow_logits = delta @ bow_W (barrier-amortized)
    mm_bow<<<dim3((NVOCAB+63)/64), dim3(256), 0, stream>>>(deltaB, bowW, o_bow);
}